// Round 4
// baseline (12376.305 us; speedup 1.0000x reference)
//
#include <hip/hip_runtime.h>
#include <hip/hip_bf16.h>

typedef unsigned short u16;
typedef unsigned int u32;

#define NN 8192
#define PXC 2560
#define MAXD 48
#define NBLK 256

typedef __attribute__((ext_vector_type(8))) short bf16x8;
typedef __attribute__((ext_vector_type(4))) float f32x4;

// ---------------- workspace layout (bytes) ----------------
static constexpr size_t SZ_PX  = (size_t)(NN + 1) * PXC * 2;   // bf16, row NN zero sentinel
static constexpr size_t SZ_ACC = (size_t)(NN + 1) * 512 * 4;   // f32
static constexpr size_t SZ_HB  = (size_t)(NN + 1) * 512 * 2;   // bf16
static constexpr size_t SZ_G   = (size_t)NN * 1536 * 4;        // f32 chain gate scratch
static constexpr size_t SZ_NW  = (size_t)5242880 * 2;          // bf16 normalized weights

static constexpr size_t OFF_PX    = 0;
static constexpr size_t OFF_QX    = OFF_PX + SZ_PX;
static constexpr size_t OFF_ACCH  = OFF_QX + SZ_PX;
static constexpr size_t OFF_ACCF  = OFF_ACCH + SZ_ACC;
static constexpr size_t OFF_ACCZ  = OFF_ACCF + SZ_ACC;
static constexpr size_t OFF_C     = OFF_ACCZ + SZ_ACC;         // Ccs / c_all, f32
static constexpr size_t OFF_HB    = OFF_C + SZ_ACC;            // Hcs / h_all, bf16
static constexpr size_t OFF_ZB    = OFF_HB + SZ_HB;            // chain z*tanh(pc), bf16
static constexpr size_t OFF_G     = OFF_ZB + SZ_HB;            // chain gates; first 8.4MB = normalized inputs (transient)
static constexpr size_t OFF_NW    = OFF_G + SZ_G;
static constexpr size_t OFF_DEPTH = OFF_NW + SZ_NW;
static constexpr size_t OFF_ORDER = OFF_DEPTH + (size_t)NN * 4;
static constexpr size_t OFF_MISC  = OFF_ORDER + (size_t)NN * 4; // counts/cursor/fcnt/pcnt/barriers
static constexpr size_t OFF_LVL   = OFF_MISC + 1024;
static constexpr size_t OFF_NB    = OFF_LVL + 512;              // normalized biases bf16 (10240)
static constexpr size_t OFF_PN    = OFF_NB + 20480;             // parent int32
static constexpr size_t OFF_PMAX  = OFF_PN + (size_t)NN * 4;
static constexpr size_t WS_TOTAL  = OFF_PMAX + (size_t)64 * 512 * 4;

// normalized-weight element offsets
#define NW_CSWX  0
#define NW_CHWX  1310720
#define NW_CSWIO 2621440
#define NW_CSWFZ 3145728
#define NW_CSWUM 3670016
#define NW_CHWH  3932160
#define NW_CHWUM 4980736

// normalized bias element offsets
#define NB_CSBX  0
#define NB_CSBIO 2560
#define NB_CSBFZ 3584
#define NB_CSBUM 4608
#define NB_CHBX  5120
#define NB_CHBH  7680
#define NB_CHBUM 9728

// ---------------- helpers ----------------
__device__ __forceinline__ float bfu(u16 u) { return __uint_as_float(((u32)u) << 16); }
__device__ __forceinline__ u16 f2bf(float f) {
    u32 u = __float_as_uint(f);
    u += 0x7fffu + ((u >> 16) & 1u);
    return (u16)(u >> 16);
}
__device__ __forceinline__ float sigf(float x) {
    x = fminf(fmaxf(x, -30.f), 30.f);
    return 1.f / (1.f + __expf(-x));
}
__device__ __forceinline__ float tanhq(float x) {
    x = fminf(fmaxf(x, -15.f), 15.f);
    return 1.f - 2.f / (__expf(2.f * x) + 1.f);
}
__device__ __forceinline__ bf16x8 cvt8(const float* p) {
    float4 a = *(const float4*)p;
    float4 b = *(const float4*)(p + 4);
    union { u32 u[4]; bf16x8 v; } r;
    r.u[0] = ((__float_as_uint(a.x) + 0x8000u) >> 16) | ((__float_as_uint(a.y) + 0x8000u) & 0xffff0000u);
    r.u[1] = ((__float_as_uint(a.z) + 0x8000u) >> 16) | ((__float_as_uint(a.w) + 0x8000u) & 0xffff0000u);
    r.u[2] = ((__float_as_uint(b.x) + 0x8000u) >> 16) | ((__float_as_uint(b.y) + 0x8000u) & 0xffff0000u);
    r.u[3] = ((__float_as_uint(b.z) + 0x8000u) >> 16) | ((__float_as_uint(b.w) + 0x8000u) & 0xffff0000u);
    return r.v;
}

// ---------------- device-scope grid barrier (sense via generation counter) ----------------
__device__ __forceinline__ void gbar(int* cnt, int* gen) {
    __syncthreads();
    if (threadIdx.x == 0) {
        __threadfence();
        int g = __hip_atomic_load(gen, __ATOMIC_RELAXED, __HIP_MEMORY_SCOPE_AGENT);
        if (__hip_atomic_fetch_add(cnt, 1, __ATOMIC_ACQ_REL, __HIP_MEMORY_SCOPE_AGENT) == NBLK - 1) {
            __hip_atomic_store(cnt, 0, __ATOMIC_RELAXED, __HIP_MEMORY_SCOPE_AGENT);
            __hip_atomic_fetch_add(gen, 1, __ATOMIC_ACQ_REL, __HIP_MEMORY_SCOPE_AGENT);
        } else {
            while (__hip_atomic_load(gen, __ATOMIC_ACQUIRE, __HIP_MEMORY_SCOPE_AGENT) == g)
                __builtin_amdgcn_s_sleep(2);
        }
        __threadfence();
    }
    __syncthreads();
}

// ---------------- dtype detection + normalization ----------------
__global__ void k_detect(const u32* __restrict__ fin, const u32* __restrict__ pin,
                         int* __restrict__ fcnt, int* __restrict__ pcnt) {
    int i = blockIdx.x * 256 + threadIdx.x;
    if (i < 4096) {
        u32 w = fin[i];
        int e = (w >> 7) & 0xFF;
        if (w != 0u && e >= 0x70 && e <= 0x8F) atomicAdd(fcnt, 1);
    }
    if (i >= 1 && i < 4096) {
        if (pin[2 * i - 1] != 0u) atomicAdd(pcnt, 1);
    }
}

__global__ void k_pnorm(const u32* __restrict__ pin, const int* __restrict__ pcnt,
                        int* __restrict__ pnorm) {
    int i = blockIdx.x * 256 + threadIdx.x;
    if (i >= NN) return;
    bool is64 = (*pcnt < 100);
    pnorm[i] = (int)(is64 ? pin[2 * i] : pin[i]);
}

// merged normalization: 15 segments, compile-time table (vec4 units)
struct NormSrcs { const void* p[15]; };
__global__ __launch_bounds__(256) void k_norm_all(NormSrcs s, u16* __restrict__ NGI,
                                                  u16* __restrict__ NW, u16* __restrict__ NB,
                                                  const int* __restrict__ fcnt) {
    const int cum[16] = {0, 1048576, 1376256, 1703936, 1835008, 1966080, 2031616, 2293760,
                         2359296, 2359936, 2360192, 2360448, 2360576, 2361216, 2361728, 2361856};
    const int dof[15] = {0, NW_CSWX / 4, NW_CHWX / 4, NW_CSWIO / 4, NW_CSWFZ / 4, NW_CSWUM / 4,
                         NW_CHWH / 4, NW_CHWUM / 4, NB_CSBX / 4, NB_CSBIO / 4, NB_CSBFZ / 4,
                         NB_CSBUM / 4, NB_CHBX / 4, NB_CHBH / 4, NB_CHBUM / 4};
    bool isbf = (*fcnt > 2048);
    int total = 2361856;
    for (int i = blockIdx.x * 256 + threadIdx.x; i < total; i += gridDim.x * 256) {
        int seg = 0;
#pragma unroll
        for (int k = 1; k < 15; ++k) if (i >= cum[k]) seg = k;
        int off = i - cum[seg];
        u16* dbase = (seg == 0) ? NGI : (seg < 8 ? NW : NB);
        ushort4* dst = (ushort4*)dbase + dof[seg] + off;
        if (isbf) {
            *dst = ((const ushort4*)s.p[seg])[off];
        } else {
            float4 v = ((const float4*)s.p[seg])[off];
            ushort4 o; o.x = f2bf(v.x); o.y = f2bf(v.y); o.z = f2bf(v.z); o.w = f2bf(v.w);
            *dst = o;
        }
    }
}

// ---------------- level schedule ----------------
__global__ void k_depth(const int* __restrict__ parent, int* __restrict__ depth) {
    int i = blockIdx.x * 256 + threadIdx.x;
    if (i >= NN) return;
    int d = 0, p = parent[i];
    while (p != NN && p >= 0 && p < NN && d < 9000) { d++; p = parent[p]; }
    depth[i] = d;
}
__global__ void k_hist(const int* __restrict__ depth, int* __restrict__ counts) {
    int i = blockIdx.x * 256 + threadIdx.x;
    if (i >= NN) return;
    int d = depth[i]; if (d > 63) d = 63;
    atomicAdd(&counts[d], 1);
}
__global__ void k_scan(const int* __restrict__ counts, int* __restrict__ lvl) {
    if (threadIdx.x == 0) {
        int s = 0; lvl[0] = 0;
        for (int d = 0; d < 64; ++d) { s += counts[d]; lvl[d + 1] = s; }
    }
}
__global__ void k_scatter(const int* __restrict__ depth, const int* __restrict__ lvl,
                          int* __restrict__ cursor, int* __restrict__ order) {
    int i = blockIdx.x * 256 + threadIdx.x;
    if (i >= NN) return;
    int d = depth[i]; if (d > 63) d = 63;
    int pos = atomicAdd(&cursor[d], 1);
    order[lvl[d] + pos] = i;
}

// ---------------- input-projection GEMM: 16x64 per wave ----------------
__global__ __launch_bounds__(256) void k_gemm_in(const u16* __restrict__ A, const u16* __restrict__ W,
                                                 const u16* __restrict__ bias, u16* __restrict__ C) {
    int wv = threadIdx.x >> 6;
    int lane = threadIdx.x & 63;
    int r = lane & 15, q = lane >> 4;
    int m0 = blockIdx.y * 16;
    int n0 = blockIdx.x * 256 + wv * 64;
    const u16* ap = A + (size_t)(m0 + r) * 512 + q * 8;
    const u16* pb[4];
#pragma unroll
    for (int jt = 0; jt < 4; ++jt) pb[jt] = W + (size_t)(n0 + jt * 16 + r) * 512 + q * 8;
    f32x4 acc[4] = {};
#pragma unroll 4
    for (int k0 = 0; k0 < 512; k0 += 32) {
        bf16x8 a = *(const bf16x8*)(ap + k0);
#pragma unroll
        for (int jt = 0; jt < 4; ++jt)
            acc[jt] = __builtin_amdgcn_mfma_f32_16x16x32_bf16(a, *(const bf16x8*)(pb[jt] + k0), acc[jt], 0, 0, 0);
    }
#pragma unroll
    for (int jt = 0; jt < 4; ++jt) {
        int c = n0 + jt * 16 + r;
        float bv = bfu(bias[c]);
        size_t basep = (size_t)(m0 + q * 4) * PXC + c;
#pragma unroll
        for (int i = 0; i < 4; ++i) C[basep + (size_t)i * PXC] = f2bf(acc[jt][i] + bv);
    }
}

// ---------------- persistent child-sum pass ----------------
__global__ __launch_bounds__(256) void cs_pass(
    const int* __restrict__ order, const int* __restrict__ lvl,
    const int* __restrict__ parent,
    float* acc_h, float* __restrict__ acc_fc, float* __restrict__ acc_zc,
    const u16* __restrict__ Wio, const u16* __restrict__ Wum, const u16* __restrict__ Wfz,
    const u16* __restrict__ bio, const u16* __restrict__ bum, const u16* __restrict__ bfz,
    const u16* __restrict__ px,
    float* __restrict__ Ccs, u16* __restrict__ HB,
    void* __restrict__ outv, const int* __restrict__ fcnt, int* bar)
{
    int lane = threadIdx.x & 63;
    int r = lane & 15, q = lane >> 4;
    int wave0 = blockIdx.x * 4 + (threadIdx.x >> 6);
    const int wstep = NBLK * 4;
    bool isbf = (*fcnt > 2048);

    for (int d = MAXD - 1; d >= 0; --d) {
        int start = lvl[d], cnt = lvl[d + 1] - start;
        if (cnt <= 0) continue;
        int ntiles = (cnt + 15) >> 4;
        int W = ntiles * 8;

        // phase 1: i,o,u gates -> c,h ; scatter h to parent's acc_h
        for (int w = wave0; w < W; w += wstep) {
            int tile = w >> 3, jb = w & 7, j0 = jb * 64;
            int tr = tile * 16 + r;
            int rA = (tr < cnt) ? order[start + tr] : NN;
            const float* pah = acc_h + (size_t)rA * 512 + q * 8;
            const float* paz = acc_zc + (size_t)rA * 512 + q * 8;
            const u16 *pbi[4], *pbo[4], *pbu[4];
#pragma unroll
            for (int jt = 0; jt < 4; ++jt) {
                int n0 = j0 + jt * 16 + r;
                pbi[jt] = Wio + (size_t)n0 * 512 + q * 8;
                pbo[jt] = Wio + (size_t)(512 + n0) * 512 + q * 8;
                pbu[jt] = Wum + (size_t)n0 * 512 + q * 8;
            }
            f32x4 ai[4] = {}, ao[4] = {}, au[4] = {};
#pragma unroll 4
            for (int ko = 0; ko < 512; ko += 32) {
                bf16x8 a_h = cvt8(pah + ko);
                bf16x8 a_z = cvt8(paz + ko);
#pragma unroll
                for (int jt = 0; jt < 4; ++jt) {
                    ai[jt] = __builtin_amdgcn_mfma_f32_16x16x32_bf16(a_h, *(const bf16x8*)(pbi[jt] + ko), ai[jt], 0, 0, 0);
                    ao[jt] = __builtin_amdgcn_mfma_f32_16x16x32_bf16(a_h, *(const bf16x8*)(pbo[jt] + ko), ao[jt], 0, 0, 0);
                    au[jt] = __builtin_amdgcn_mfma_f32_16x16x32_bf16(a_z, *(const bf16x8*)(pbu[jt] + ko), au[jt], 0, 0, 0);
                }
            }
#pragma unroll
            for (int i2 = 0; i2 < 4; ++i2) {
                int ti = tile * 16 + q * 4 + i2;
                if (ti >= cnt) continue;
                int ni = order[start + ti];
                int p = parent[ni];
                size_t pxb = (size_t)ni * PXC, nb = (size_t)ni * 512, pb = (size_t)p * 512;
#pragma unroll
                for (int jt = 0; jt < 4; ++jt) {
                    int c = j0 + jt * 16 + r;
                    float ig = sigf(bfu(px[pxb + c]) + ai[jt][i2] + bfu(bio[c]));
                    float og = sigf(bfu(px[pxb + 1024 + c]) + ao[jt][i2] + bfu(bio[512 + c]));
                    float uu = tanhq(bfu(px[pxb + 2048 + c]) + au[jt][i2] + bfu(bum[c]));
                    float cc = ig * uu + acc_fc[nb + c];
                    float h = og * tanhq(cc);
                    Ccs[nb + c] = cc;
                    HB[nb + c] = f2bf(h);
                    atomicAdd(&acc_h[pb + c], h);
                    if (ni == 0) {
                        if (isbf) ((u16*)outv)[c] = f2bf(h);
                        else ((float*)outv)[c] = h;
                    }
                }
            }
        }
        gbar(bar, bar + 1);

        // phase 2: f,z on h ; scatter f*c, z*tanh(c) to parent's acc
        for (int w = wave0; w < W; w += wstep) {
            int tile = w >> 3, jb = w & 7, j0 = jb * 64;
            int tr = tile * 16 + r;
            int rA = (tr < cnt) ? order[start + tr] : NN;
            const u16* pa = HB + (size_t)rA * 512 + q * 8;
            const u16 *pbf[4], *pbz[4];
#pragma unroll
            for (int jt = 0; jt < 4; ++jt) {
                int n0 = j0 + jt * 16 + r;
                pbf[jt] = Wfz + (size_t)n0 * 512 + q * 8;
                pbz[jt] = Wfz + (size_t)(512 + n0) * 512 + q * 8;
            }
            f32x4 af[4] = {}, az[4] = {};
#pragma unroll 4
            for (int ko = 0; ko < 512; ko += 32) {
                bf16x8 a = *(const bf16x8*)(pa + ko);
#pragma unroll
                for (int jt = 0; jt < 4; ++jt) {
                    af[jt] = __builtin_amdgcn_mfma_f32_16x16x32_bf16(a, *(const bf16x8*)(pbf[jt] + ko), af[jt], 0, 0, 0);
                    az[jt] = __builtin_amdgcn_mfma_f32_16x16x32_bf16(a, *(const bf16x8*)(pbz[jt] + ko), az[jt], 0, 0, 0);
                }
            }
#pragma unroll
            for (int i2 = 0; i2 < 4; ++i2) {
                int ti = tile * 16 + q * 4 + i2;
                if (ti >= cnt) continue;
                int ni = order[start + ti];
                int p = parent[ni];
                size_t nb = (size_t)ni * 512, pb = (size_t)p * 512, ppx = (size_t)p * PXC;
#pragma unroll
                for (int jt = 0; jt < 4; ++jt) {
                    int c = j0 + jt * 16 + r;
                    float cT = Ccs[nb + c];
                    float f = sigf(bfu(px[ppx + 512 + c]) + af[jt][i2] + bfu(bfz[c]));
                    atomicAdd(&acc_fc[pb + c], f * cT);
                    float z = sigf(bfu(px[ppx + 1536 + c]) + az[jt][i2] + bfu(bfz[512 + c]));
                    atomicAdd(&acc_zc[pb + c], z * tanhq(cT));
                }
            }
        }
        gbar(bar, bar + 1);
    }
}

// ---------------- persistent chain pass (+ fused final max) ----------------
__global__ __launch_bounds__(256) void ch_pass(
    const int* __restrict__ order, const int* __restrict__ lvl,
    const int* __restrict__ parent,
    u16* __restrict__ HB, float* __restrict__ Call,
    const u16* __restrict__ Wh, const u16* __restrict__ Wum,
    const u16* __restrict__ bh, const u16* __restrict__ bum,
    const u16* __restrict__ qx,
    float* __restrict__ G, u16* __restrict__ ZB,
    float* __restrict__ pmax,
    void* __restrict__ outv, const int* __restrict__ fcnt, int* bar)
{
    int lane = threadIdx.x & 63;
    int r = lane & 15, q = lane >> 4;
    int wave0 = blockIdx.x * 4 + (threadIdx.x >> 6);
    const int wstep = NBLK * 4;
    bool isbf = (*fcnt > 2048);

    for (int d = 0; d < MAXD; ++d) {
        int start = lvl[d], cnt = lvl[d + 1] - start;
        if (cnt <= 0) continue;
        int ntiles = (cnt + 15) >> 4;
        int W = ntiles * 8;

        // phase 1: 4-gate GEMM from parent's h; G = i,o,f pre-acts; ZB = sig(z)*tanh(pc)
        for (int w = wave0; w < W; w += wstep) {
            int tile = w >> 3, jb = w & 7, j0 = jb * 64;
            int tr = tile * 16 + r;
            int nod = (tr < cnt) ? order[start + tr] : -1;
            int rP = (nod < 0) ? NN : parent[nod];
            const u16* pa = HB + (size_t)rP * 512 + q * 8;
            const u16 *pbi[4], *pbo[4], *pbf[4], *pbz[4];
#pragma unroll
            for (int jt = 0; jt < 4; ++jt) {
                int n0 = j0 + jt * 16 + r;
                pbi[jt] = Wh + (size_t)n0 * 512 + q * 8;
                pbo[jt] = Wh + (size_t)(512 + n0) * 512 + q * 8;
                pbf[jt] = Wh + (size_t)(1024 + n0) * 512 + q * 8;
                pbz[jt] = Wh + (size_t)(1536 + n0) * 512 + q * 8;
            }
            f32x4 gi[4] = {}, go[4] = {}, gf[4] = {}, gz[4] = {};
#pragma unroll 2
            for (int ko = 0; ko < 512; ko += 32) {
                bf16x8 a = *(const bf16x8*)(pa + ko);
#pragma unroll
                for (int jt = 0; jt < 4; ++jt) {
                    gi[jt] = __builtin_amdgcn_mfma_f32_16x16x32_bf16(a, *(const bf16x8*)(pbi[jt] + ko), gi[jt], 0, 0, 0);
                    go[jt] = __builtin_amdgcn_mfma_f32_16x16x32_bf16(a, *(const bf16x8*)(pbo[jt] + ko), go[jt], 0, 0, 0);
                    gf[jt] = __builtin_amdgcn_mfma_f32_16x16x32_bf16(a, *(const bf16x8*)(pbf[jt] + ko), gf[jt], 0, 0, 0);
                    gz[jt] = __builtin_amdgcn_mfma_f32_16x16x32_bf16(a, *(const bf16x8*)(pbz[jt] + ko), gz[jt], 0, 0, 0);
                }
            }
#pragma unroll
            for (int i2 = 0; i2 < 4; ++i2) {
                int ti = tile * 16 + q * 4 + i2;
                if (ti >= cnt) continue;
                int ni = order[start + ti];
                int p = parent[ni];
                size_t gb = (size_t)ni * 1536, nb = (size_t)ni * 512, pb = (size_t)p * 512;
                size_t qb = (size_t)ni * PXC;
#pragma unroll
                for (int jt = 0; jt < 4; ++jt) {
                    int c = j0 + jt * 16 + r;
                    G[gb + c]        = gi[jt][i2] + bfu(bh[c]);
                    G[gb + 512 + c]  = go[jt][i2] + bfu(bh[512 + c]);
                    G[gb + 1024 + c] = gf[jt][i2] + bfu(bh[1024 + c]);
                    float zg = sigf(bfu(qx[qb + 1536 + c]) + gz[jt][i2] + bfu(bh[1536 + c]));
                    ZB[nb + c] = f2bf(zg * tanhq(Call[pb + c]));
                }
            }
        }
        gbar(bar, bar + 1);

        // phase 2: u-GEMM on ZB; gates -> c,h
        for (int w = wave0; w < W; w += wstep) {
            int tile = w >> 3, jb = w & 7, j0 = jb * 64;
            int tr = tile * 16 + r;
            int rA = (tr < cnt) ? order[start + tr] : NN;
            const u16* pa = ZB + (size_t)rA * 512 + q * 8;
            const u16* pbu[4];
#pragma unroll
            for (int jt = 0; jt < 4; ++jt)
                pbu[jt] = Wum + (size_t)(j0 + jt * 16 + r) * 512 + q * 8;
            f32x4 au[4] = {};
#pragma unroll 4
            for (int ko = 0; ko < 512; ko += 32) {
                bf16x8 a = *(const bf16x8*)(pa + ko);
#pragma unroll
                for (int jt = 0; jt < 4; ++jt)
                    au[jt] = __builtin_amdgcn_mfma_f32_16x16x32_bf16(a, *(const bf16x8*)(pbu[jt] + ko), au[jt], 0, 0, 0);
            }
#pragma unroll
            for (int i2 = 0; i2 < 4; ++i2) {
                int ti = tile * 16 + q * 4 + i2;
                if (ti >= cnt) continue;
                int ni = order[start + ti];
                int p = parent[ni];
                size_t gb = (size_t)ni * 1536, nb = (size_t)ni * 512, pb = (size_t)p * 512;
                size_t qb = (size_t)ni * PXC;
#pragma unroll
                for (int jt = 0; jt < 4; ++jt) {
                    int c = j0 + jt * 16 + r;
                    float uu = tanhq(bfu(qx[qb + 2048 + c]) + au[jt][i2] + bfu(bum[c]));
                    float ig = sigf(bfu(qx[qb + c]) + G[gb + c]);
                    float og = sigf(bfu(qx[qb + 512 + c]) + G[gb + 512 + c]);
                    float fg = sigf(bfu(qx[qb + 1024 + c]) + G[gb + 1024 + c]);
                    float pc = Call[pb + c];
                    float cc = ig * uu + fg * pc;
                    float h = og * tanhq(cc);
                    Call[nb + c] = cc;
                    HB[nb + c] = f2bf(h);
                }
            }
        }
        gbar(bar, bar + 1);
    }

    // fused final max over all h rows
    if (blockIdx.x < 64) {
        int b = blockIdx.x, t = threadIdx.x;
        float m1 = -1e30f, m2 = -1e30f;
        for (int rr = b * 128; rr < b * 128 + 128; ++rr) {
            m1 = fmaxf(m1, bfu(HB[(size_t)rr * 512 + t]));
            m2 = fmaxf(m2, bfu(HB[(size_t)rr * 512 + t + 256]));
        }
        pmax[(size_t)b * 512 + t] = m1; pmax[(size_t)b * 512 + t + 256] = m2;
    }
    gbar(bar, bar + 1);
    if (blockIdx.x == 0) {
        int t = threadIdx.x;
#pragma unroll
        for (int half = 0; half < 2; ++half) {
            int j = t + half * 256;
            float m = -1e30f;
            for (int b = 0; b < 64; ++b) m = fmaxf(m, pmax[(size_t)b * 512 + j]);
            if (isbf) ((u16*)outv)[512 + j] = f2bf(m);
            else ((float*)outv)[512 + j] = m;
        }
    }
}

__global__ void k_wsfail(u16* out) {
    int i = blockIdx.x * 256 + threadIdx.x;
    if (i < 1024) out[i] = f2bf(12345.f);
}

// ---------------- launch ----------------
extern "C" void kernel_launch(void* const* d_in, const int* in_sizes, int n_in,
                              void* d_out, int out_size, void* d_ws, size_t ws_size,
                              hipStream_t stream) {
    char* base = (char*)d_ws;
    u16* px = (u16*)(base + OFF_PX);
    u16* qx = (u16*)(base + OFF_QX);
    float* acc_h = (float*)(base + OFF_ACCH);
    float* acc_fc = (float*)(base + OFF_ACCF);
    float* acc_zc = (float*)(base + OFF_ACCZ);
    float* Call = (float*)(base + OFF_C);
    u16* HB = (u16*)(base + OFF_HB);
    u16* ZB = (u16*)(base + OFF_ZB);
    float* G = (float*)(base + OFF_G);
    u16* NGI = (u16*)(base + OFF_G);
    u16* NW = (u16*)(base + OFF_NW);
    int* depth = (int*)(base + OFF_DEPTH);
    int* order = (int*)(base + OFF_ORDER);
    int* counts = (int*)(base + OFF_MISC);
    int* cursor = counts + 64;
    int* fcnt = counts + 128;
    int* pcnt = counts + 129;
    int* barCS = counts + 132;   // cnt,gen
    int* barCH = counts + 136;   // cnt,gen
    int* lvl = (int*)(base + OFF_LVL);
    u16* NB = (u16*)(base + OFF_NB);
    int* pnorm = (int*)(base + OFF_PN);
    float* pmax = (float*)(base + OFF_PMAX);

    if (ws_size < WS_TOTAL) { k_wsfail<<<4, 256, 0, stream>>>((u16*)d_out); return; }

    hipMemsetAsync(base + OFF_MISC, 0, 1024, stream);
    hipMemsetAsync(base + OFF_ACCH, 0, 3 * SZ_ACC, stream);       // acc_h/fc/zc
    hipMemsetAsync(base + OFF_C, 0, SZ_ACC, stream);              // Ccs/Call
    hipMemsetAsync(base + OFF_HB, 0, 2 * SZ_HB, stream);          // HB + ZB
    hipMemsetAsync((char*)(px + (size_t)NN * PXC), 0, PXC * 2, stream);
    hipMemsetAsync((char*)(qx + (size_t)NN * PXC), 0, PXC * 2, stream);

    // dtype detect + merged normalize
    k_detect<<<16, 256, 0, stream>>>((const u32*)d_in[0], (const u32*)d_in[1], fcnt, pcnt);
    k_pnorm<<<32, 256, 0, stream>>>((const u32*)d_in[1], pcnt, pnorm);
    NormSrcs srcs;
    srcs.p[0] = d_in[0];  srcs.p[1] = d_in[2];  srcs.p[2] = d_in[10]; srcs.p[3] = d_in[4];
    srcs.p[4] = d_in[6];  srcs.p[5] = d_in[8];  srcs.p[6] = d_in[12]; srcs.p[7] = d_in[14];
    srcs.p[8] = d_in[3];  srcs.p[9] = d_in[5];  srcs.p[10] = d_in[7]; srcs.p[11] = d_in[9];
    srcs.p[12] = d_in[11]; srcs.p[13] = d_in[13]; srcs.p[14] = d_in[15];
    k_norm_all<<<2048, 256, 0, stream>>>(srcs, NGI, NW, NB, fcnt);

    // level schedule
    k_depth<<<32, 256, 0, stream>>>(pnorm, depth);
    k_hist<<<32, 256, 0, stream>>>(depth, counts);
    k_scan<<<1, 64, 0, stream>>>(counts, lvl);
    k_scatter<<<32, 256, 0, stream>>>(depth, lvl, cursor, order);

    // input projections
    dim3 gg(PXC / 256, NN / 16);
    k_gemm_in<<<gg, 256, 0, stream>>>(NGI, NW + NW_CSWX, NB + NB_CSBX, px);
    k_gemm_in<<<gg, 256, 0, stream>>>(NGI, NW + NW_CHWX, NB + NB_CHBX, qx);

    // persistent child-sum pass (deepest -> root)
    cs_pass<<<NBLK, 256, 0, stream>>>(order, lvl, pnorm,
                                      acc_h, acc_fc, acc_zc,
                                      NW + NW_CSWIO, NW + NW_CSWUM, NW + NW_CSWFZ,
                                      NB + NB_CSBIO, NB + NB_CSBUM, NB + NB_CSBFZ,
                                      px, Call, HB, d_out, fcnt, barCS);

    // persistent chain pass (root -> leaves) + fused max
    ch_pass<<<NBLK, 256, 0, stream>>>(order, lvl, pnorm,
                                      HB, Call,
                                      NW + NW_CHWH, NW + NW_CHWUM,
                                      NB + NB_CHBH, NB + NB_CHBUM,
                                      qx, G, ZB, pmax, d_out, fcnt, barCH);
}

// Round 5
// 11148.073 us; speedup vs baseline: 1.1102x; 1.1102x over previous
//
#include <hip/hip_runtime.h>
#include <hip/hip_bf16.h>

typedef unsigned short u16;
typedef unsigned int u32;

#define NN 8192
#define PXC 2560
#define MAXD 48
#define NBLK 128
#define NGRP 16
#define GRPSZ 8
#define TBLK 512

typedef __attribute__((ext_vector_type(8))) short bf16x8;
typedef __attribute__((ext_vector_type(4))) float f32x4;

// ---------------- workspace layout (bytes) ----------------
static constexpr size_t SZ_PX  = (size_t)(NN + 1) * PXC * 2;   // bf16, row NN zero sentinel
static constexpr size_t SZ_ACC = (size_t)(NN + 1) * 512 * 4;   // f32
static constexpr size_t SZ_HB  = (size_t)(NN + 1) * 512 * 2;   // bf16
static constexpr size_t SZ_G   = (size_t)NN * 1536 * 4;        // transient normalized-inputs region
static constexpr size_t SZ_NW  = (size_t)5242880 * 2;          // bf16 normalized weights

static constexpr size_t OFF_PX    = 0;
static constexpr size_t OFF_QX    = OFF_PX + SZ_PX;
static constexpr size_t OFF_ACCH  = OFF_QX + SZ_PX;
static constexpr size_t OFF_ACCF  = OFF_ACCH + SZ_ACC;
static constexpr size_t OFF_ACCZ  = OFF_ACCF + SZ_ACC;
static constexpr size_t OFF_C     = OFF_ACCZ + SZ_ACC;         // c_all (chain), f32
static constexpr size_t OFF_HB    = OFF_C + SZ_ACC;            // h_all (chain), bf16
static constexpr size_t OFF_ZB    = OFF_HB + SZ_HB;            // unused (kept for layout stability)
static constexpr size_t OFF_G     = OFF_ZB + SZ_HB;            // transient normalized inputs
static constexpr size_t OFF_NW    = OFF_G + SZ_G;
static constexpr size_t OFF_DEPTH = OFF_NW + SZ_NW;
static constexpr size_t OFF_ORDER = OFF_DEPTH + (size_t)NN * 4;
static constexpr size_t OFF_MISC  = OFF_ORDER + (size_t)NN * 4;
static constexpr size_t OFF_LVL   = OFF_MISC + 1024;
static constexpr size_t OFF_NB    = OFF_LVL + 512;
static constexpr size_t OFF_PN    = OFF_NB + 20480;
static constexpr size_t OFF_PMAX  = OFF_PN + (size_t)NN * 4;   // f32 128*512
static constexpr size_t OFF_BAR   = OFF_PMAX + (size_t)128 * 512 * 4;
static constexpr size_t WS_TOTAL  = OFF_BAR + 8192;

#define NW_CSWX  0
#define NW_CHWX  1310720
#define NW_CSWIO 2621440
#define NW_CSWFZ 3145728
#define NW_CSWUM 3670016
#define NW_CHWH  3932160
#define NW_CHWUM 4980736

#define NB_CSBX  0
#define NB_CSBIO 2560
#define NB_CSBFZ 3584
#define NB_CSBUM 4608
#define NB_CHBX  5120
#define NB_CHBH  7680
#define NB_CHBUM 9728

// ---------------- helpers ----------------
__device__ __forceinline__ float bfu(u16 u) { return __uint_as_float(((u32)u) << 16); }
__device__ __forceinline__ u16 f2bf(float f) {
    u32 u = __float_as_uint(f);
    u += 0x7fffu + ((u >> 16) & 1u);
    return (u16)(u >> 16);
}
__device__ __forceinline__ float sigf(float x) {
    x = fminf(fmaxf(x, -30.f), 30.f);
    return 1.f / (1.f + __expf(-x));
}
__device__ __forceinline__ float tanhq(float x) {
    x = fminf(fmaxf(x, -15.f), 15.f);
    return 1.f - 2.f / (__expf(2.f * x) + 1.f);
}

// ---------------- hierarchical grid barrier: 16 groups x 8 + root ----------------
// bar[0]=gen, bar[32]=root, bar[64+g*32]=group counters (separate cachelines)
__device__ __forceinline__ void gbar(int* bar) {
    __syncthreads();
    if (threadIdx.x == 0) {
        __threadfence();
        int g = blockIdx.x & (NGRP - 1);
        int gen = __hip_atomic_load(&bar[0], __ATOMIC_RELAXED, __HIP_MEMORY_SCOPE_AGENT);
        if (__hip_atomic_fetch_add(&bar[64 + g * 32], 1, __ATOMIC_ACQ_REL, __HIP_MEMORY_SCOPE_AGENT) == GRPSZ - 1) {
            if (__hip_atomic_fetch_add(&bar[32], 1, __ATOMIC_ACQ_REL, __HIP_MEMORY_SCOPE_AGENT) == NGRP - 1) {
#pragma unroll
                for (int k = 0; k < NGRP; ++k)
                    __hip_atomic_store(&bar[64 + k * 32], 0, __ATOMIC_RELAXED, __HIP_MEMORY_SCOPE_AGENT);
                __hip_atomic_store(&bar[32], 0, __ATOMIC_RELAXED, __HIP_MEMORY_SCOPE_AGENT);
                __hip_atomic_fetch_add(&bar[0], 1, __ATOMIC_RELEASE, __HIP_MEMORY_SCOPE_AGENT);
            } else {
                while (__hip_atomic_load(&bar[0], __ATOMIC_ACQUIRE, __HIP_MEMORY_SCOPE_AGENT) == gen)
                    __builtin_amdgcn_s_sleep(1);
            }
        } else {
            while (__hip_atomic_load(&bar[0], __ATOMIC_ACQUIRE, __HIP_MEMORY_SCOPE_AGENT) == gen)
                __builtin_amdgcn_s_sleep(1);
        }
        __threadfence();
    }
    __syncthreads();
}

// ---------------- dtype detection + normalization ----------------
__global__ void k_detect(const u32* __restrict__ fin, const u32* __restrict__ pin,
                         int* __restrict__ fcnt, int* __restrict__ pcnt) {
    int i = blockIdx.x * 256 + threadIdx.x;
    if (i < 4096) {
        u32 w = fin[i];
        int e = (w >> 7) & 0xFF;
        if (w != 0u && e >= 0x70 && e <= 0x8F) atomicAdd(fcnt, 1);
    }
    if (i >= 1 && i < 4096) {
        if (pin[2 * i - 1] != 0u) atomicAdd(pcnt, 1);
    }
}

__global__ void k_pnorm(const u32* __restrict__ pin, const int* __restrict__ pcnt,
                        int* __restrict__ pnorm) {
    int i = blockIdx.x * 256 + threadIdx.x;
    if (i >= NN) return;
    bool is64 = (*pcnt < 100);
    pnorm[i] = (int)(is64 ? pin[2 * i] : pin[i]);
}

struct NormSrcs { const void* p[15]; };
__global__ __launch_bounds__(256) void k_norm_all(NormSrcs s, u16* __restrict__ NGI,
                                                  u16* __restrict__ NW, u16* __restrict__ NB,
                                                  const int* __restrict__ fcnt) {
    const int cum[16] = {0, 1048576, 1376256, 1703936, 1835008, 1966080, 2031616, 2293760,
                         2359296, 2359936, 2360192, 2360448, 2360576, 2361216, 2361728, 2361856};
    const int dof[15] = {0, NW_CSWX / 4, NW_CHWX / 4, NW_CSWIO / 4, NW_CSWFZ / 4, NW_CSWUM / 4,
                         NW_CHWH / 4, NW_CHWUM / 4, NB_CSBX / 4, NB_CSBIO / 4, NB_CSBFZ / 4,
                         NB_CSBUM / 4, NB_CHBX / 4, NB_CHBH / 4, NB_CHBUM / 4};
    bool isbf = (*fcnt > 2048);
    int total = 2361856;
    for (int i = blockIdx.x * 256 + threadIdx.x; i < total; i += gridDim.x * 256) {
        int seg = 0;
#pragma unroll
        for (int k = 1; k < 15; ++k) if (i >= cum[k]) seg = k;
        int off = i - cum[seg];
        u16* dbase = (seg == 0) ? NGI : (seg < 8 ? NW : NB);
        ushort4* dst = (ushort4*)dbase + dof[seg] + off;
        if (isbf) {
            *dst = ((const ushort4*)s.p[seg])[off];
        } else {
            float4 v = ((const float4*)s.p[seg])[off];
            ushort4 o; o.x = f2bf(v.x); o.y = f2bf(v.y); o.z = f2bf(v.z); o.w = f2bf(v.w);
            *dst = o;
        }
    }
}

// ---------------- level schedule ----------------
__global__ void k_depth(const int* __restrict__ parent, int* __restrict__ depth) {
    int i = blockIdx.x * 256 + threadIdx.x;
    if (i >= NN) return;
    int d = 0, p = parent[i];
    while (p != NN && p >= 0 && p < NN && d < 9000) { d++; p = parent[p]; }
    depth[i] = d;
}
__global__ void k_hist(const int* __restrict__ depth, int* __restrict__ counts) {
    int i = blockIdx.x * 256 + threadIdx.x;
    if (i >= NN) return;
    int d = depth[i]; if (d > 63) d = 63;
    atomicAdd(&counts[d], 1);
}
__global__ void k_scan(const int* __restrict__ counts, int* __restrict__ lvl) {
    if (threadIdx.x == 0) {
        int s = 0; lvl[0] = 0;
        for (int d = 0; d < 64; ++d) { s += counts[d]; lvl[d + 1] = s; }
    }
}
__global__ void k_scatter(const int* __restrict__ depth, const int* __restrict__ lvl,
                          int* __restrict__ cursor, int* __restrict__ order) {
    int i = blockIdx.x * 256 + threadIdx.x;
    if (i >= NN) return;
    int d = depth[i]; if (d > 63) d = 63;
    int pos = atomicAdd(&cursor[d], 1);
    order[lvl[d] + pos] = i;
}

// ---------------- input-projection GEMM: 32x64 per wave (2 m-tiles reuse B) ----------------
__global__ __launch_bounds__(256) void k_gemm_in(const u16* __restrict__ A, const u16* __restrict__ W,
                                                 const u16* __restrict__ bias, u16* __restrict__ C) {
    int wv = threadIdx.x >> 6;
    int lane = threadIdx.x & 63;
    int r = lane & 15, q = lane >> 4;
    int m0 = blockIdx.y * 32;
    int n0 = blockIdx.x * 256 + wv * 64;
    const u16* ap0 = A + (size_t)(m0 + r) * 512 + q * 8;
    const u16* ap1 = ap0 + 16 * 512;
    const u16* pb[4];
#pragma unroll
    for (int jt = 0; jt < 4; ++jt) pb[jt] = W + (size_t)(n0 + jt * 16 + r) * 512 + q * 8;
    f32x4 acc0[4] = {}, acc1[4] = {};
#pragma unroll 4
    for (int k0 = 0; k0 < 512; k0 += 32) {
        bf16x8 a0 = *(const bf16x8*)(ap0 + k0);
        bf16x8 a1 = *(const bf16x8*)(ap1 + k0);
#pragma unroll
        for (int jt = 0; jt < 4; ++jt) {
            bf16x8 b = *(const bf16x8*)(pb[jt] + k0);
            acc0[jt] = __builtin_amdgcn_mfma_f32_16x16x32_bf16(a0, b, acc0[jt], 0, 0, 0);
            acc1[jt] = __builtin_amdgcn_mfma_f32_16x16x32_bf16(a1, b, acc1[jt], 0, 0, 0);
        }
    }
#pragma unroll
    for (int jt = 0; jt < 4; ++jt) {
        int c = n0 + jt * 16 + r;
        float bv = bfu(bias[c]);
        size_t b0 = (size_t)(m0 + q * 4) * PXC + c;
        size_t b1 = (size_t)(m0 + 16 + q * 4) * PXC + c;
#pragma unroll
        for (int i = 0; i < 4; ++i) {
            C[b0 + (size_t)i * PXC] = f2bf(acc0[jt][i] + bv);
            C[b1 + (size_t)i * PXC] = f2bf(acc1[jt][i] + bv);
        }
    }
}

// ---------------- persistent child-sum pass (1 barrier / non-empty level) ----------------
__global__ __launch_bounds__(TBLK) void cs_pass(
    const int* __restrict__ order, const int* __restrict__ lvl,
    const int* __restrict__ parent,
    float* acc_h, float* __restrict__ acc_fc, float* __restrict__ acc_zc,
    const u16* __restrict__ Wio, const u16* __restrict__ Wum, const u16* __restrict__ Wfz,
    const u16* __restrict__ bio, const u16* __restrict__ bum, const u16* __restrict__ bfz,
    const u16* __restrict__ px,
    void* __restrict__ outv, const int* __restrict__ fcnt, int* bar)
{
    __shared__ __align__(16) u16 AH[16 * 520];
    __shared__ __align__(16) u16 AZ[16 * 520];
    int lane = threadIdx.x & 63;
    int r = lane & 15, q = lane >> 4;
    int w = threadIdx.x >> 6;           // 0..7, owns 64 output cols
    int cb = w * 64;
    bool isbf = (*fcnt > 2048);

    for (int d = MAXD - 1; d >= 0; --d) {
        int start = lvl[d], cnt = lvl[d + 1] - start;
        if (cnt <= 0) continue;
        int ntiles = (cnt + 15) >> 4;

        for (int tile = blockIdx.x; tile < ntiles; tile += NBLK) {
            // ---- stage A operands: acc_h/acc_zc rows -> bf16 LDS ----
            __syncthreads();
#pragma unroll
            for (int it = 0; it < 4; ++it) {
                int g = threadIdx.x + it * TBLK;     // 0..2047
                int row = g >> 7, f = g & 127;
                int ti = tile * 16 + row;
                int nod = (ti < cnt) ? order[start + ti] : NN;
                float4 vh = *(const float4*)(acc_h + (size_t)nod * 512 + f * 4);
                float4 vz = *(const float4*)(acc_zc + (size_t)nod * 512 + f * 4);
                ushort4 oh, oz;
                oh.x = f2bf(vh.x); oh.y = f2bf(vh.y); oh.z = f2bf(vh.z); oh.w = f2bf(vh.w);
                oz.x = f2bf(vz.x); oz.y = f2bf(vz.y); oz.z = f2bf(vz.z); oz.w = f2bf(vz.w);
                *(ushort4*)&AH[row * 520 + f * 4] = oh;
                *(ushort4*)&AZ[row * 520 + f * 4] = oz;
            }
            __syncthreads();

            // ---- phase 1: i,o,u GEMMs -> c,h ; scatter h ----
            const u16 *pbi[4], *pbo[4], *pbu[4];
#pragma unroll
            for (int jt = 0; jt < 4; ++jt) {
                int n = cb + jt * 16 + r;
                pbi[jt] = Wio + (size_t)n * 512 + q * 8;
                pbo[jt] = Wio + (size_t)(512 + n) * 512 + q * 8;
                pbu[jt] = Wum + (size_t)n * 512 + q * 8;
            }
            f32x4 ai[4] = {}, ao[4] = {}, au[4] = {};
#pragma unroll 4
            for (int ko = 0; ko < 512; ko += 32) {
                bf16x8 a_h = *(const bf16x8*)&AH[r * 520 + ko + q * 8];
                bf16x8 a_z = *(const bf16x8*)&AZ[r * 520 + ko + q * 8];
#pragma unroll
                for (int jt = 0; jt < 4; ++jt) {
                    ai[jt] = __builtin_amdgcn_mfma_f32_16x16x32_bf16(a_h, *(const bf16x8*)(pbi[jt] + ko), ai[jt], 0, 0, 0);
                    ao[jt] = __builtin_amdgcn_mfma_f32_16x16x32_bf16(a_h, *(const bf16x8*)(pbo[jt] + ko), ao[jt], 0, 0, 0);
                    au[jt] = __builtin_amdgcn_mfma_f32_16x16x32_bf16(a_z, *(const bf16x8*)(pbu[jt] + ko), au[jt], 0, 0, 0);
                }
            }
            f32x4 cr[4], hr[4];
#pragma unroll
            for (int i2 = 0; i2 < 4; ++i2) {
                int ti = tile * 16 + q * 4 + i2;
                bool ok = (ti < cnt);
                int ni = ok ? order[start + ti] : NN;
                int p = ok ? parent[ni] : NN;
                size_t pxb = (size_t)ni * PXC, nb = (size_t)ni * 512, pb = (size_t)p * 512;
#pragma unroll
                for (int jt = 0; jt < 4; ++jt) {
                    int c = cb + jt * 16 + r;
                    if (ok) {
                        float ig = sigf(bfu(px[pxb + c]) + ai[jt][i2] + bfu(bio[c]));
                        float og = sigf(bfu(px[pxb + 1024 + c]) + ao[jt][i2] + bfu(bio[512 + c]));
                        float uu = tanhq(bfu(px[pxb + 2048 + c]) + au[jt][i2] + bfu(bum[c]));
                        float cc = ig * uu + acc_fc[nb + c];
                        float h = og * tanhq(cc);
                        cr[jt][i2] = cc; hr[jt][i2] = h;
                        atomicAdd(&acc_h[pb + c], h);
                        if (ni == 0) {
                            if (isbf) ((u16*)outv)[c] = f2bf(h);
                            else ((float*)outv)[c] = h;
                        }
                    } else { cr[jt][i2] = 0.f; hr[jt][i2] = 0.f; }
                }
            }
            __syncthreads();   // all waves done reading AH/AZ
            // write h tile into AH (reuse as phase-2 A)
#pragma unroll
            for (int i2 = 0; i2 < 4; ++i2) {
                int tl = q * 4 + i2;
#pragma unroll
                for (int jt = 0; jt < 4; ++jt)
                    AH[tl * 520 + cb + jt * 16 + r] = f2bf(hr[jt][i2]);
            }
            __syncthreads();

            // ---- phase 2: f,z GEMMs on h ; scatter to parent's accumulators ----
            const u16 *pbf[4], *pbz[4];
#pragma unroll
            for (int jt = 0; jt < 4; ++jt) {
                int n = cb + jt * 16 + r;
                pbf[jt] = Wfz + (size_t)n * 512 + q * 8;
                pbz[jt] = Wfz + (size_t)(512 + n) * 512 + q * 8;
            }
            f32x4 af[4] = {}, az[4] = {};
#pragma unroll 4
            for (int ko = 0; ko < 512; ko += 32) {
                bf16x8 a = *(const bf16x8*)&AH[r * 520 + ko + q * 8];
#pragma unroll
                for (int jt = 0; jt < 4; ++jt) {
                    af[jt] = __builtin_amdgcn_mfma_f32_16x16x32_bf16(a, *(const bf16x8*)(pbf[jt] + ko), af[jt], 0, 0, 0);
                    az[jt] = __builtin_amdgcn_mfma_f32_16x16x32_bf16(a, *(const bf16x8*)(pbz[jt] + ko), az[jt], 0, 0, 0);
                }
            }
#pragma unroll
            for (int i2 = 0; i2 < 4; ++i2) {
                int ti = tile * 16 + q * 4 + i2;
                if (ti >= cnt) continue;
                int ni = order[start + ti];
                int p = parent[ni];
                size_t pb = (size_t)p * 512, ppx = (size_t)p * PXC;
#pragma unroll
                for (int jt = 0; jt < 4; ++jt) {
                    int c = cb + jt * 16 + r;
                    float cc = cr[jt][i2];
                    float f = sigf(bfu(px[ppx + 512 + c]) + af[jt][i2] + bfu(bfz[c]));
                    atomicAdd(&acc_fc[pb + c], f * cc);
                    float z = sigf(bfu(px[ppx + 1536 + c]) + az[jt][i2] + bfu(bfz[512 + c]));
                    atomicAdd(&acc_zc[pb + c], z * tanhq(cc));
                }
            }
        }
        gbar(bar);
    }
}

// ---------------- persistent chain pass (+ fused final max) ----------------
__global__ __launch_bounds__(TBLK) void ch_pass(
    const int* __restrict__ order, const int* __restrict__ lvl,
    const int* __restrict__ parent,
    u16* __restrict__ HB, float* __restrict__ Call,
    const u16* __restrict__ Wh, const u16* __restrict__ Wum,
    const u16* __restrict__ bh, const u16* __restrict__ bum,
    const u16* __restrict__ qx,
    float* __restrict__ pmax,
    void* __restrict__ outv, const int* __restrict__ fcnt, int* bar)
{
    __shared__ __align__(16) u16 PH[16 * 520];   // parent-h (phase1 A), reused as ZB tile (phase2 A)
    int lane = threadIdx.x & 63;
    int r = lane & 15, q = lane >> 4;
    int w = threadIdx.x >> 6;
    int cb = w * 64;
    bool isbf = (*fcnt > 2048);

    for (int d = 0; d < MAXD; ++d) {
        int start = lvl[d], cnt = lvl[d + 1] - start;
        if (cnt <= 0) continue;
        int ntiles = (cnt + 15) >> 4;

        for (int tile = blockIdx.x; tile < ntiles; tile += NBLK) {
            // ---- stage parent-h rows ----
            __syncthreads();
#pragma unroll
            for (int it = 0; it < 4; ++it) {
                int g = threadIdx.x + it * TBLK;
                int row = g >> 7, f = g & 127;
                int ti = tile * 16 + row;
                int nod = (ti < cnt) ? order[start + ti] : -1;
                int prow = (nod < 0) ? NN : parent[nod];
                *(ushort4*)&PH[row * 520 + f * 4] =
                    *(const ushort4*)(HB + (size_t)prow * 512 + f * 4);
            }
            __syncthreads();

            // ---- phase 1: 4-gate GEMM -> sigma gates (regs) + ZB (regs) ----
            const u16 *pbi[4], *pbo[4], *pbf[4], *pbz[4];
#pragma unroll
            for (int jt = 0; jt < 4; ++jt) {
                int n = cb + jt * 16 + r;
                pbi[jt] = Wh + (size_t)n * 512 + q * 8;
                pbo[jt] = Wh + (size_t)(512 + n) * 512 + q * 8;
                pbf[jt] = Wh + (size_t)(1024 + n) * 512 + q * 8;
                pbz[jt] = Wh + (size_t)(1536 + n) * 512 + q * 8;
            }
            f32x4 gi[4] = {}, go[4] = {}, gf[4] = {}, gz[4] = {};
#pragma unroll 2
            for (int ko = 0; ko < 512; ko += 32) {
                bf16x8 a = *(const bf16x8*)&PH[r * 520 + ko + q * 8];
#pragma unroll
                for (int jt = 0; jt < 4; ++jt) {
                    gi[jt] = __builtin_amdgcn_mfma_f32_16x16x32_bf16(a, *(const bf16x8*)(pbi[jt] + ko), gi[jt], 0, 0, 0);
                    go[jt] = __builtin_amdgcn_mfma_f32_16x16x32_bf16(a, *(const bf16x8*)(pbo[jt] + ko), go[jt], 0, 0, 0);
                    gf[jt] = __builtin_amdgcn_mfma_f32_16x16x32_bf16(a, *(const bf16x8*)(pbf[jt] + ko), gf[jt], 0, 0, 0);
                    gz[jt] = __builtin_amdgcn_mfma_f32_16x16x32_bf16(a, *(const bf16x8*)(pbz[jt] + ko), gz[jt], 0, 0, 0);
                }
            }
            f32x4 si[4], so[4], sf[4], zb[4];
#pragma unroll
            for (int i2 = 0; i2 < 4; ++i2) {
                int ti = tile * 16 + q * 4 + i2;
                bool ok = (ti < cnt);
                int ni = ok ? order[start + ti] : NN;
                int p = ok ? parent[ni] : NN;
                size_t qb = (size_t)ni * PXC, pb = (size_t)p * 512;
#pragma unroll
                for (int jt = 0; jt < 4; ++jt) {
                    int c = cb + jt * 16 + r;
                    if (ok) {
                        si[jt][i2] = sigf(bfu(qx[qb + c]) + gi[jt][i2] + bfu(bh[c]));
                        so[jt][i2] = sigf(bfu(qx[qb + 512 + c]) + go[jt][i2] + bfu(bh[512 + c]));
                        sf[jt][i2] = sigf(bfu(qx[qb + 1024 + c]) + gf[jt][i2] + bfu(bh[1024 + c]));
                        float zg = sigf(bfu(qx[qb + 1536 + c]) + gz[jt][i2] + bfu(bh[1536 + c]));
                        zb[jt][i2] = zg * tanhq(Call[pb + c]);
                    } else { si[jt][i2] = so[jt][i2] = sf[jt][i2] = 0.f; zb[jt][i2] = 0.f; }
                }
            }
            __syncthreads();   // all waves done reading PH
#pragma unroll
            for (int i2 = 0; i2 < 4; ++i2) {
                int tl = q * 4 + i2;
#pragma unroll
                for (int jt = 0; jt < 4; ++jt)
                    PH[tl * 520 + cb + jt * 16 + r] = f2bf(zb[jt][i2]);
            }
            __syncthreads();

            // ---- phase 2: u-GEMM on ZB ; gates -> c,h ----
            const u16* pbu[4];
#pragma unroll
            for (int jt = 0; jt < 4; ++jt)
                pbu[jt] = Wum + (size_t)(cb + jt * 16 + r) * 512 + q * 8;
            f32x4 auc[4] = {};
#pragma unroll 4
            for (int ko = 0; ko < 512; ko += 32) {
                bf16x8 a = *(const bf16x8*)&PH[r * 520 + ko + q * 8];
#pragma unroll
                for (int jt = 0; jt < 4; ++jt)
                    auc[jt] = __builtin_amdgcn_mfma_f32_16x16x32_bf16(a, *(const bf16x8*)(pbu[jt] + ko), auc[jt], 0, 0, 0);
            }
#pragma unroll
            for (int i2 = 0; i2 < 4; ++i2) {
                int ti = tile * 16 + q * 4 + i2;
                if (ti >= cnt) continue;
                int ni = order[start + ti];
                int p = parent[ni];
                size_t qb = (size_t)ni * PXC, nb = (size_t)ni * 512, pb = (size_t)p * 512;
#pragma unroll
                for (int jt = 0; jt < 4; ++jt) {
                    int c = cb + jt * 16 + r;
                    float uu = tanhq(bfu(qx[qb + 2048 + c]) + auc[jt][i2] + bfu(bum[c]));
                    float pc = Call[pb + c];
                    float cc = si[jt][i2] * uu + sf[jt][i2] * pc;
                    float h = so[jt][i2] * tanhq(cc);
                    Call[nb + c] = cc;
                    HB[nb + c] = f2bf(h);
                }
            }
        }
        gbar(bar);
    }

    // ---- fused final max over all h rows ----
    gbar(bar);
    {
        int b = blockIdx.x, t = threadIdx.x;   // t: 0..511 = column
        float m = -1e30f;
        for (int rr = b * 64; rr < b * 64 + 64; ++rr)
            m = fmaxf(m, bfu(HB[(size_t)rr * 512 + t]));
        pmax[(size_t)b * 512 + t] = m;
    }
    gbar(bar);
    if (blockIdx.x == 0) {
        int j = threadIdx.x;
        float m = -1e30f;
        for (int b = 0; b < NBLK; ++b) m = fmaxf(m, pmax[(size_t)b * 512 + j]);
        if (isbf) ((u16*)outv)[512 + j] = f2bf(m);
        else ((float*)outv)[512 + j] = m;
    }
}

__global__ void k_wsfail(u16* out) {
    int i = blockIdx.x * 256 + threadIdx.x;
    if (i < 1024) out[i] = f2bf(12345.f);
}

// ---------------- launch ----------------
extern "C" void kernel_launch(void* const* d_in, const int* in_sizes, int n_in,
                              void* d_out, int out_size, void* d_ws, size_t ws_size,
                              hipStream_t stream) {
    char* base = (char*)d_ws;
    u16* px = (u16*)(base + OFF_PX);
    u16* qx = (u16*)(base + OFF_QX);
    float* acc_h = (float*)(base + OFF_ACCH);
    float* acc_fc = (float*)(base + OFF_ACCF);
    float* acc_zc = (float*)(base + OFF_ACCZ);
    float* Call = (float*)(base + OFF_C);
    u16* HB = (u16*)(base + OFF_HB);
    u16* NGI = (u16*)(base + OFF_G);
    u16* NW = (u16*)(base + OFF_NW);
    int* depth = (int*)(base + OFF_DEPTH);
    int* order = (int*)(base + OFF_ORDER);
    int* counts = (int*)(base + OFF_MISC);
    int* cursor = counts + 64;
    int* fcnt = counts + 128;
    int* pcnt = counts + 129;
    int* lvl = (int*)(base + OFF_LVL);
    u16* NB = (u16*)(base + OFF_NB);
    int* pnorm = (int*)(base + OFF_PN);
    float* pmax = (float*)(base + OFF_PMAX);
    int* barCS = (int*)(base + OFF_BAR);
    int* barCH = (int*)(base + OFF_BAR + 4096);

    if (ws_size < WS_TOTAL) { k_wsfail<<<4, 256, 0, stream>>>((u16*)d_out); return; }

    hipMemsetAsync(base + OFF_MISC, 0, 1024, stream);
    hipMemsetAsync(base + OFF_BAR, 0, 8192, stream);
    hipMemsetAsync(base + OFF_ACCH, 0, 3 * SZ_ACC, stream);                 // acc_h/fc/zc (all rows + sentinel)
    hipMemsetAsync((char*)(px + (size_t)NN * PXC), 0, PXC * 2, stream);     // px sentinel row
    hipMemsetAsync((char*)(HB + (size_t)NN * 512), 0, 512 * 2, stream);     // h sentinel row
    hipMemsetAsync((char*)(Call + (size_t)NN * 512), 0, 512 * 4, stream);   // c sentinel row

    // dtype detect + merged normalize
    k_detect<<<16, 256, 0, stream>>>((const u32*)d_in[0], (const u32*)d_in[1], fcnt, pcnt);
    k_pnorm<<<32, 256, 0, stream>>>((const u32*)d_in[1], pcnt, pnorm);
    NormSrcs srcs;
    srcs.p[0] = d_in[0];  srcs.p[1] = d_in[2];  srcs.p[2] = d_in[10]; srcs.p[3] = d_in[4];
    srcs.p[4] = d_in[6];  srcs.p[5] = d_in[8];  srcs.p[6] = d_in[12]; srcs.p[7] = d_in[14];
    srcs.p[8] = d_in[3];  srcs.p[9] = d_in[5];  srcs.p[10] = d_in[7]; srcs.p[11] = d_in[9];
    srcs.p[12] = d_in[11]; srcs.p[13] = d_in[13]; srcs.p[14] = d_in[15];
    k_norm_all<<<2048, 256, 0, stream>>>(srcs, NGI, NW, NB, fcnt);

    // level schedule
    k_depth<<<32, 256, 0, stream>>>(pnorm, depth);
    k_hist<<<32, 256, 0, stream>>>(depth, counts);
    k_scan<<<1, 64, 0, stream>>>(counts, lvl);
    k_scatter<<<32, 256, 0, stream>>>(depth, lvl, cursor, order);

    // input projections
    dim3 gg(PXC / 256, NN / 32);
    k_gemm_in<<<gg, 256, 0, stream>>>(NGI, NW + NW_CSWX, NB + NB_CSBX, px);
    k_gemm_in<<<gg, 256, 0, stream>>>(NGI, NW + NW_CHWX, NB + NB_CHBX, qx);

    // persistent passes
    cs_pass<<<NBLK, TBLK, 0, stream>>>(order, lvl, pnorm,
                                       acc_h, acc_fc, acc_zc,
                                       NW + NW_CSWIO, NW + NW_CSWUM, NW + NW_CSWFZ,
                                       NB + NB_CSBIO, NB + NB_CSBUM, NB + NB_CSBFZ,
                                       px, d_out, fcnt, barCS);
    ch_pass<<<NBLK, TBLK, 0, stream>>>(order, lvl, pnorm,
                                       HB, Call,
                                       NW + NW_CHWH, NW + NW_CHWUM,
                                       NB + NB_CHBH, NB + NB_CHBUM,
                                       qx, pmax, d_out, fcnt, barCH);
}

// Round 6
// 4466.453 us; speedup vs baseline: 2.7709x; 2.4960x over previous
//
#include <hip/hip_runtime.h>
#include <hip/hip_bf16.h>

typedef unsigned short u16;
typedef unsigned int u32;

#define NN 8192
#define PXC 2560
#define MAXD 48
#define LVL_GRID 96
#define TBLK 512

typedef __attribute__((ext_vector_type(8))) short bf16x8;
typedef __attribute__((ext_vector_type(4))) float f32x4;

// ---------------- workspace layout (bytes) ----------------
static constexpr size_t SZ_PX  = (size_t)(NN + 1) * PXC * 2;   // bf16, row NN zero sentinel
static constexpr size_t SZ_ACC = (size_t)(NN + 1) * 512 * 4;   // f32
static constexpr size_t SZ_HB  = (size_t)(NN + 1) * 512 * 2;   // bf16
static constexpr size_t SZ_G   = (size_t)NN * 1536 * 4;        // transient normalized-inputs region
static constexpr size_t SZ_NW  = (size_t)5242880 * 2;          // bf16 normalized weights

static constexpr size_t OFF_PX    = 0;
static constexpr size_t OFF_QX    = OFF_PX + SZ_PX;
static constexpr size_t OFF_ACCH  = OFF_QX + SZ_PX;
static constexpr size_t OFF_ACCF  = OFF_ACCH + SZ_ACC;
static constexpr size_t OFF_ACCZ  = OFF_ACCF + SZ_ACC;
static constexpr size_t OFF_C     = OFF_ACCZ + SZ_ACC;         // c_all (chain), f32
static constexpr size_t OFF_HB    = OFF_C + SZ_ACC;            // h_all (chain), bf16
static constexpr size_t OFF_ZB    = OFF_HB + SZ_HB;            // spare
static constexpr size_t OFF_G     = OFF_ZB + SZ_HB;            // transient normalized inputs
static constexpr size_t OFF_NW    = OFF_G + SZ_G;
static constexpr size_t OFF_DEPTH = OFF_NW + SZ_NW;
static constexpr size_t OFF_ORDER = OFF_DEPTH + (size_t)NN * 4;
static constexpr size_t OFF_MISC  = OFF_ORDER + (size_t)NN * 4;
static constexpr size_t OFF_LVL   = OFF_MISC + 1024;
static constexpr size_t OFF_NB    = OFF_LVL + 512;
static constexpr size_t OFF_PN    = OFF_NB + 20480;
static constexpr size_t OFF_PMAX  = OFF_PN + (size_t)NN * 4;   // f32 64*512
static constexpr size_t WS_TOTAL  = OFF_PMAX + (size_t)128 * 512 * 4;

#define NW_CSWX  0
#define NW_CHWX  1310720
#define NW_CSWIO 2621440
#define NW_CSWFZ 3145728
#define NW_CSWUM 3670016
#define NW_CHWH  3932160
#define NW_CHWUM 4980736

#define NB_CSBX  0
#define NB_CSBIO 2560
#define NB_CSBFZ 3584
#define NB_CSBUM 4608
#define NB_CHBX  5120
#define NB_CHBH  7680
#define NB_CHBUM 9728

// ---------------- helpers ----------------
__device__ __forceinline__ float bfu(u16 u) { return __uint_as_float(((u32)u) << 16); }
__device__ __forceinline__ u16 f2bf(float f) {
    u32 u = __float_as_uint(f);
    u += 0x7fffu + ((u >> 16) & 1u);
    return (u16)(u >> 16);
}
__device__ __forceinline__ float sigf(float x) {
    x = fminf(fmaxf(x, -30.f), 30.f);
    return 1.f / (1.f + __expf(-x));
}
__device__ __forceinline__ float tanhq(float x) {
    x = fminf(fmaxf(x, -15.f), 15.f);
    return 1.f - 2.f / (__expf(2.f * x) + 1.f);
}

// ---------------- dtype detection + normalization ----------------
__global__ void k_detect(const u32* __restrict__ fin, const u32* __restrict__ pin,
                         int* __restrict__ fcnt, int* __restrict__ pcnt) {
    int i = blockIdx.x * 256 + threadIdx.x;
    if (i < 4096) {
        u32 w = fin[i];
        int e = (w >> 7) & 0xFF;
        if (w != 0u && e >= 0x70 && e <= 0x8F) atomicAdd(fcnt, 1);
    }
    if (i >= 1 && i < 4096) {
        if (pin[2 * i - 1] != 0u) atomicAdd(pcnt, 1);
    }
}

__global__ void k_pnorm(const u32* __restrict__ pin, const int* __restrict__ pcnt,
                        int* __restrict__ pnorm) {
    int i = blockIdx.x * 256 + threadIdx.x;
    if (i >= NN) return;
    bool is64 = (*pcnt < 100);
    pnorm[i] = (int)(is64 ? pin[2 * i] : pin[i]);
}

struct NormSrcs { const void* p[15]; };
__global__ __launch_bounds__(256) void k_norm_all(NormSrcs s, u16* __restrict__ NGI,
                                                  u16* __restrict__ NW, u16* __restrict__ NB,
                                                  const int* __restrict__ fcnt) {
    const int cum[16] = {0, 1048576, 1376256, 1703936, 1835008, 1966080, 2031616, 2293760,
                         2359296, 2359936, 2360192, 2360448, 2360576, 2361216, 2361728, 2361856};
    const int dof[15] = {0, NW_CSWX / 4, NW_CHWX / 4, NW_CSWIO / 4, NW_CSWFZ / 4, NW_CSWUM / 4,
                         NW_CHWH / 4, NW_CHWUM / 4, NB_CSBX / 4, NB_CSBIO / 4, NB_CSBFZ / 4,
                         NB_CSBUM / 4, NB_CHBX / 4, NB_CHBH / 4, NB_CHBUM / 4};
    bool isbf = (*fcnt > 2048);
    int total = 2361856;
    for (int i = blockIdx.x * 256 + threadIdx.x; i < total; i += gridDim.x * 256) {
        int seg = 0;
#pragma unroll
        for (int k = 1; k < 15; ++k) if (i >= cum[k]) seg = k;
        int off = i - cum[seg];
        u16* dbase = (seg == 0) ? NGI : (seg < 8 ? NW : NB);
        ushort4* dst = (ushort4*)dbase + dof[seg] + off;
        if (isbf) {
            *dst = ((const ushort4*)s.p[seg])[off];
        } else {
            float4 v = ((const float4*)s.p[seg])[off];
            ushort4 o; o.x = f2bf(v.x); o.y = f2bf(v.y); o.z = f2bf(v.z); o.w = f2bf(v.w);
            *dst = o;
        }
    }
}

// ---------------- level schedule ----------------
__global__ void k_depth(const int* __restrict__ parent, int* __restrict__ depth) {
    int i = blockIdx.x * 256 + threadIdx.x;
    if (i >= NN) return;
    int d = 0, p = parent[i];
    while (p != NN && p >= 0 && p < NN && d < 9000) { d++; p = parent[p]; }
    depth[i] = d;
}
__global__ void k_hist(const int* __restrict__ depth, int* __restrict__ counts) {
    int i = blockIdx.x * 256 + threadIdx.x;
    if (i >= NN) return;
    int d = depth[i]; if (d > 63) d = 63;
    atomicAdd(&counts[d], 1);
}
__global__ void k_scan(const int* __restrict__ counts, int* __restrict__ lvl) {
    if (threadIdx.x == 0) {
        int s = 0; lvl[0] = 0;
        for (int d = 0; d < 64; ++d) { s += counts[d]; lvl[d + 1] = s; }
    }
}
__global__ void k_scatter(const int* __restrict__ depth, const int* __restrict__ lvl,
                          int* __restrict__ cursor, int* __restrict__ order) {
    int i = blockIdx.x * 256 + threadIdx.x;
    if (i >= NN) return;
    int d = depth[i]; if (d > 63) d = 63;
    int pos = atomicAdd(&cursor[d], 1);
    order[lvl[d] + pos] = i;
}

// ---------------- input-projection GEMM: 32x64 per wave (2 m-tiles reuse B) ----------------
__global__ __launch_bounds__(256) void k_gemm_in(const u16* __restrict__ A, const u16* __restrict__ W,
                                                 const u16* __restrict__ bias, u16* __restrict__ C) {
    int wv = threadIdx.x >> 6;
    int lane = threadIdx.x & 63;
    int r = lane & 15, q = lane >> 4;
    int m0 = blockIdx.y * 32;
    int n0 = blockIdx.x * 256 + wv * 64;
    const u16* ap0 = A + (size_t)(m0 + r) * 512 + q * 8;
    const u16* ap1 = ap0 + 16 * 512;
    const u16* pb[4];
#pragma unroll
    for (int jt = 0; jt < 4; ++jt) pb[jt] = W + (size_t)(n0 + jt * 16 + r) * 512 + q * 8;
    f32x4 acc0[4] = {}, acc1[4] = {};
#pragma unroll 4
    for (int k0 = 0; k0 < 512; k0 += 32) {
        bf16x8 a0 = *(const bf16x8*)(ap0 + k0);
        bf16x8 a1 = *(const bf16x8*)(ap1 + k0);
#pragma unroll
        for (int jt = 0; jt < 4; ++jt) {
            bf16x8 b = *(const bf16x8*)(pb[jt] + k0);
            acc0[jt] = __builtin_amdgcn_mfma_f32_16x16x32_bf16(a0, b, acc0[jt], 0, 0, 0);
            acc1[jt] = __builtin_amdgcn_mfma_f32_16x16x32_bf16(a1, b, acc1[jt], 0, 0, 0);
        }
    }
#pragma unroll
    for (int jt = 0; jt < 4; ++jt) {
        int c = n0 + jt * 16 + r;
        float bv = bfu(bias[c]);
        size_t b0 = (size_t)(m0 + q * 4) * PXC + c;
        size_t b1 = (size_t)(m0 + 16 + q * 4) * PXC + c;
#pragma unroll
        for (int i = 0; i < 4; ++i) {
            C[b0 + (size_t)i * PXC] = f2bf(acc0[jt][i] + bv);
            C[b1 + (size_t)i * PXC] = f2bf(acc1[jt][i] + bv);
        }
    }
}

// ---------------- child-sum: one fused kernel per level ----------------
__global__ __launch_bounds__(TBLK) void cs_lvl(
    int d,
    const int* __restrict__ order, const int* __restrict__ lvl,
    const int* __restrict__ parent,
    float* acc_h, float* __restrict__ acc_fc, float* __restrict__ acc_zc,
    const u16* __restrict__ Wio, const u16* __restrict__ Wum, const u16* __restrict__ Wfz,
    const u16* __restrict__ bio, const u16* __restrict__ bum, const u16* __restrict__ bfz,
    const u16* __restrict__ px,
    void* __restrict__ outv, const int* __restrict__ fcnt)
{
    int start = lvl[d], cnt = lvl[d + 1] - start;
    if (cnt <= 0) return;
    int ntiles = (cnt + 15) >> 4;
    if (blockIdx.x >= (u32)ntiles && blockIdx.x >= LVL_GRID) return;

    __shared__ __align__(16) u16 AH[16 * 520];
    __shared__ __align__(16) u16 AZ[16 * 520];
    int lane = threadIdx.x & 63;
    int r = lane & 15, q = lane >> 4;
    int w = threadIdx.x >> 6;           // 0..7, owns 64 output cols
    int cb = w * 64;
    bool isbf = (*fcnt > 2048);

    for (int tile = blockIdx.x; tile < ntiles; tile += LVL_GRID) {
        // ---- stage A operands: acc_h/acc_zc rows -> bf16 LDS ----
        __syncthreads();
#pragma unroll
        for (int it = 0; it < 4; ++it) {
            int g = threadIdx.x + it * TBLK;     // 0..2047
            int row = g >> 7, f = g & 127;
            int ti = tile * 16 + row;
            int nod = (ti < cnt) ? order[start + ti] : NN;
            float4 vh = *(const float4*)(acc_h + (size_t)nod * 512 + f * 4);
            float4 vz = *(const float4*)(acc_zc + (size_t)nod * 512 + f * 4);
            ushort4 oh, oz;
            oh.x = f2bf(vh.x); oh.y = f2bf(vh.y); oh.z = f2bf(vh.z); oh.w = f2bf(vh.w);
            oz.x = f2bf(vz.x); oz.y = f2bf(vz.y); oz.z = f2bf(vz.z); oz.w = f2bf(vz.w);
            *(ushort4*)&AH[row * 520 + f * 4] = oh;
            *(ushort4*)&AZ[row * 520 + f * 4] = oz;
        }
        __syncthreads();

        // ---- phase 1: i,o,u GEMMs -> c,h ; scatter h to parent's acc_h ----
        const u16 *pbi[4], *pbo[4], *pbu[4];
#pragma unroll
        for (int jt = 0; jt < 4; ++jt) {
            int n = cb + jt * 16 + r;
            pbi[jt] = Wio + (size_t)n * 512 + q * 8;
            pbo[jt] = Wio + (size_t)(512 + n) * 512 + q * 8;
            pbu[jt] = Wum + (size_t)n * 512 + q * 8;
        }
        f32x4 ai[4] = {}, ao[4] = {}, au[4] = {};
#pragma unroll 4
        for (int ko = 0; ko < 512; ko += 32) {
            bf16x8 a_h = *(const bf16x8*)&AH[r * 520 + ko + q * 8];
            bf16x8 a_z = *(const bf16x8*)&AZ[r * 520 + ko + q * 8];
#pragma unroll
            for (int jt = 0; jt < 4; ++jt) {
                ai[jt] = __builtin_amdgcn_mfma_f32_16x16x32_bf16(a_h, *(const bf16x8*)(pbi[jt] + ko), ai[jt], 0, 0, 0);
                ao[jt] = __builtin_amdgcn_mfma_f32_16x16x32_bf16(a_h, *(const bf16x8*)(pbo[jt] + ko), ao[jt], 0, 0, 0);
                au[jt] = __builtin_amdgcn_mfma_f32_16x16x32_bf16(a_z, *(const bf16x8*)(pbu[jt] + ko), au[jt], 0, 0, 0);
            }
        }
        f32x4 cr[4], hr[4];
#pragma unroll
        for (int i2 = 0; i2 < 4; ++i2) {
            int ti = tile * 16 + q * 4 + i2;
            bool ok = (ti < cnt);
            int ni = ok ? order[start + ti] : NN;
            int p = ok ? parent[ni] : NN;
            size_t pxb = (size_t)ni * PXC, nb = (size_t)ni * 512, pb = (size_t)p * 512;
#pragma unroll
            for (int jt = 0; jt < 4; ++jt) {
                int c = cb + jt * 16 + r;
                if (ok) {
                    float ig = sigf(bfu(px[pxb + c]) + ai[jt][i2] + bfu(bio[c]));
                    float og = sigf(bfu(px[pxb + 1024 + c]) + ao[jt][i2] + bfu(bio[512 + c]));
                    float uu = tanhq(bfu(px[pxb + 2048 + c]) + au[jt][i2] + bfu(bum[c]));
                    float cc = ig * uu + acc_fc[nb + c];
                    float h = og * tanhq(cc);
                    cr[jt][i2] = cc; hr[jt][i2] = h;
                    atomicAdd(&acc_h[pb + c], h);
                    if (ni == 0) {
                        if (isbf) ((u16*)outv)[c] = f2bf(h);
                        else ((float*)outv)[c] = h;
                    }
                } else { cr[jt][i2] = 0.f; hr[jt][i2] = 0.f; }
            }
        }
        __syncthreads();   // all waves done reading AH/AZ
        // write h tile into AH (reuse as phase-2 A operand)
#pragma unroll
        for (int i2 = 0; i2 < 4; ++i2) {
            int tl = q * 4 + i2;
#pragma unroll
            for (int jt = 0; jt < 4; ++jt)
                AH[tl * 520 + cb + jt * 16 + r] = f2bf(hr[jt][i2]);
        }
        __syncthreads();

        // ---- phase 2: f,z GEMMs on h ; scatter to parent's accumulators ----
        const u16 *pbf[4], *pbz[4];
#pragma unroll
        for (int jt = 0; jt < 4; ++jt) {
            int n = cb + jt * 16 + r;
            pbf[jt] = Wfz + (size_t)n * 512 + q * 8;
            pbz[jt] = Wfz + (size_t)(512 + n) * 512 + q * 8;
        }
        f32x4 af[4] = {}, az[4] = {};
#pragma unroll 4
        for (int ko = 0; ko < 512; ko += 32) {
            bf16x8 a = *(const bf16x8*)&AH[r * 520 + ko + q * 8];
#pragma unroll
            for (int jt = 0; jt < 4; ++jt) {
                af[jt] = __builtin_amdgcn_mfma_f32_16x16x32_bf16(a, *(const bf16x8*)(pbf[jt] + ko), af[jt], 0, 0, 0);
                az[jt] = __builtin_amdgcn_mfma_f32_16x16x32_bf16(a, *(const bf16x8*)(pbz[jt] + ko), az[jt], 0, 0, 0);
            }
        }
#pragma unroll
        for (int i2 = 0; i2 < 4; ++i2) {
            int ti = tile * 16 + q * 4 + i2;
            if (ti >= cnt) continue;
            int ni = order[start + ti];
            int p = parent[ni];
            size_t pb = (size_t)p * 512, ppx = (size_t)p * PXC;
#pragma unroll
            for (int jt = 0; jt < 4; ++jt) {
                int c = cb + jt * 16 + r;
                float cc = cr[jt][i2];
                float f = sigf(bfu(px[ppx + 512 + c]) + af[jt][i2] + bfu(bfz[c]));
                atomicAdd(&acc_fc[pb + c], f * cc);
                float z = sigf(bfu(px[ppx + 1536 + c]) + az[jt][i2] + bfu(bfz[512 + c]));
                atomicAdd(&acc_zc[pb + c], z * tanhq(cc));
            }
        }
    }
}

// ---------------- chain: one fused kernel per level ----------------
__global__ __launch_bounds__(TBLK) void ch_lvl(
    int d,
    const int* __restrict__ order, const int* __restrict__ lvl,
    const int* __restrict__ parent,
    u16* __restrict__ HB, float* __restrict__ Call,
    const u16* __restrict__ Wh, const u16* __restrict__ Wum,
    const u16* __restrict__ bh, const u16* __restrict__ bum,
    const u16* __restrict__ qx)
{
    int start = lvl[d], cnt = lvl[d + 1] - start;
    if (cnt <= 0) return;
    int ntiles = (cnt + 15) >> 4;
    if (blockIdx.x >= (u32)ntiles && blockIdx.x >= LVL_GRID) return;

    __shared__ __align__(16) u16 PH[16 * 520];   // parent-h, reused as ZB tile
    int lane = threadIdx.x & 63;
    int r = lane & 15, q = lane >> 4;
    int w = threadIdx.x >> 6;
    int cb = w * 64;

    for (int tile = blockIdx.x; tile < ntiles; tile += LVL_GRID) {
        // ---- stage parent-h rows ----
        __syncthreads();
#pragma unroll
        for (int it = 0; it < 4; ++it) {
            int g = threadIdx.x + it * TBLK;
            int row = g >> 7, f = g & 127;
            int ti = tile * 16 + row;
            int nod = (ti < cnt) ? order[start + ti] : -1;
            int prow = (nod < 0) ? NN : parent[nod];
            *(ushort4*)&PH[row * 520 + f * 4] =
                *(const ushort4*)(HB + (size_t)prow * 512 + f * 4);
        }
        __syncthreads();

        // ---- phase 1: 4-gate GEMM -> sigma gates (regs) + ZB (regs) ----
        const u16 *pbi[4], *pbo[4], *pbf[4], *pbz[4];
#pragma unroll
        for (int jt = 0; jt < 4; ++jt) {
            int n = cb + jt * 16 + r;
            pbi[jt] = Wh + (size_t)n * 512 + q * 8;
            pbo[jt] = Wh + (size_t)(512 + n) * 512 + q * 8;
            pbf[jt] = Wh + (size_t)(1024 + n) * 512 + q * 8;
            pbz[jt] = Wh + (size_t)(1536 + n) * 512 + q * 8;
        }
        f32x4 gi[4] = {}, go[4] = {}, gf[4] = {}, gz[4] = {};
#pragma unroll 2
        for (int ko = 0; ko < 512; ko += 32) {
            bf16x8 a = *(const bf16x8*)&PH[r * 520 + ko + q * 8];
#pragma unroll
            for (int jt = 0; jt < 4; ++jt) {
                gi[jt] = __builtin_amdgcn_mfma_f32_16x16x32_bf16(a, *(const bf16x8*)(pbi[jt] + ko), gi[jt], 0, 0, 0);
                go[jt] = __builtin_amdgcn_mfma_f32_16x16x32_bf16(a, *(const bf16x8*)(pbo[jt] + ko), go[jt], 0, 0, 0);
                gf[jt] = __builtin_amdgcn_mfma_f32_16x16x32_bf16(a, *(const bf16x8*)(pbf[jt] + ko), gf[jt], 0, 0, 0);
                gz[jt] = __builtin_amdgcn_mfma_f32_16x16x32_bf16(a, *(const bf16x8*)(pbz[jt] + ko), gz[jt], 0, 0, 0);
            }
        }
        f32x4 si[4], so[4], sf[4], zb[4];
#pragma unroll
        for (int i2 = 0; i2 < 4; ++i2) {
            int ti = tile * 16 + q * 4 + i2;
            bool ok = (ti < cnt);
            int ni = ok ? order[start + ti] : NN;
            int p = ok ? parent[ni] : NN;
            size_t qb = (size_t)ni * PXC, pb = (size_t)p * 512;
#pragma unroll
            for (int jt = 0; jt < 4; ++jt) {
                int c = cb + jt * 16 + r;
                if (ok) {
                    si[jt][i2] = sigf(bfu(qx[qb + c]) + gi[jt][i2] + bfu(bh[c]));
                    so[jt][i2] = sigf(bfu(qx[qb + 512 + c]) + go[jt][i2] + bfu(bh[512 + c]));
                    sf[jt][i2] = sigf(bfu(qx[qb + 1024 + c]) + gf[jt][i2] + bfu(bh[1024 + c]));
                    float zg = sigf(bfu(qx[qb + 1536 + c]) + gz[jt][i2] + bfu(bh[1536 + c]));
                    zb[jt][i2] = zg * tanhq(Call[pb + c]);
                } else { si[jt][i2] = so[jt][i2] = sf[jt][i2] = 0.f; zb[jt][i2] = 0.f; }
            }
        }
        __syncthreads();   // all waves done reading PH
#pragma unroll
        for (int i2 = 0; i2 < 4; ++i2) {
            int tl = q * 4 + i2;
#pragma unroll
            for (int jt = 0; jt < 4; ++jt)
                PH[tl * 520 + cb + jt * 16 + r] = f2bf(zb[jt][i2]);
        }
        __syncthreads();

        // ---- phase 2: u-GEMM on ZB ; gates -> c,h ----
        const u16* pbu[4];
#pragma unroll
        for (int jt = 0; jt < 4; ++jt)
            pbu[jt] = Wum + (size_t)(cb + jt * 16 + r) * 512 + q * 8;
        f32x4 auc[4] = {};
#pragma unroll 4
        for (int ko = 0; ko < 512; ko += 32) {
            bf16x8 a = *(const bf16x8*)&PH[r * 520 + ko + q * 8];
#pragma unroll
            for (int jt = 0; jt < 4; ++jt)
                auc[jt] = __builtin_amdgcn_mfma_f32_16x16x32_bf16(a, *(const bf16x8*)(pbu[jt] + ko), auc[jt], 0, 0, 0);
        }
#pragma unroll
        for (int i2 = 0; i2 < 4; ++i2) {
            int ti = tile * 16 + q * 4 + i2;
            if (ti >= cnt) continue;
            int ni = order[start + ti];
            int p = parent[ni];
            size_t qb = (size_t)ni * PXC, nb = (size_t)ni * 512, pb = (size_t)p * 512;
#pragma unroll
            for (int jt = 0; jt < 4; ++jt) {
                int c = cb + jt * 16 + r;
                float uu = tanhq(bfu(qx[qb + 2048 + c]) + auc[jt][i2] + bfu(bum[c]));
                float pc = Call[pb + c];
                float cc = si[jt][i2] * uu + sf[jt][i2] * pc;
                float h = so[jt][i2] * tanhq(cc);
                Call[nb + c] = cc;
                HB[nb + c] = f2bf(h);
            }
        }
    }
}

// ---------------- final max reduce ----------------
__global__ __launch_bounds__(256) void k_maxA(const u16* __restrict__ HB, float* __restrict__ pmax) {
    int b = blockIdx.x, t = threadIdx.x;
    float m1 = -1e30f, m2 = -1e30f;
    for (int rr = b * 128; rr < b * 128 + 128; ++rr) {
        m1 = fmaxf(m1, bfu(HB[(size_t)rr * 512 + t]));
        m2 = fmaxf(m2, bfu(HB[(size_t)rr * 512 + t + 256]));
    }
    pmax[(size_t)b * 512 + t] = m1; pmax[(size_t)b * 512 + t + 256] = m2;
}
__global__ void k_maxB(const float* __restrict__ pmax, void* __restrict__ outv,
                       const int* __restrict__ fcnt) {
    int j = threadIdx.x;
    float m = -1e30f;
    for (int b = 0; b < 64; ++b) m = fmaxf(m, pmax[(size_t)b * 512 + j]);
    bool isbf = (*fcnt > 2048);
    if (isbf) ((u16*)outv)[512 + j] = f2bf(m);
    else ((float*)outv)[512 + j] = m;
}

__global__ void k_wsfail(u16* out) {
    int i = blockIdx.x * 256 + threadIdx.x;
    if (i < 1024) out[i] = f2bf(12345.f);
}

// ---------------- launch ----------------
extern "C" void kernel_launch(void* const* d_in, const int* in_sizes, int n_in,
                              void* d_out, int out_size, void* d_ws, size_t ws_size,
                              hipStream_t stream) {
    char* base = (char*)d_ws;
    u16* px = (u16*)(base + OFF_PX);
    u16* qx = (u16*)(base + OFF_QX);
    float* acc_h = (float*)(base + OFF_ACCH);
    float* acc_fc = (float*)(base + OFF_ACCF);
    float* acc_zc = (float*)(base + OFF_ACCZ);
    float* Call = (float*)(base + OFF_C);
    u16* HB = (u16*)(base + OFF_HB);
    u16* NGI = (u16*)(base + OFF_G);
    u16* NW = (u16*)(base + OFF_NW);
    int* depth = (int*)(base + OFF_DEPTH);
    int* order = (int*)(base + OFF_ORDER);
    int* counts = (int*)(base + OFF_MISC);
    int* cursor = counts + 64;
    int* fcnt = counts + 128;
    int* pcnt = counts + 129;
    int* lvl = (int*)(base + OFF_LVL);
    u16* NB = (u16*)(base + OFF_NB);
    int* pnorm = (int*)(base + OFF_PN);
    float* pmax = (float*)(base + OFF_PMAX);

    if (ws_size < WS_TOTAL) { k_wsfail<<<4, 256, 0, stream>>>((u16*)d_out); return; }

    hipMemsetAsync(base + OFF_MISC, 0, 1024, stream);
    hipMemsetAsync(base + OFF_ACCH, 0, 3 * SZ_ACC, stream);                 // acc_h/fc/zc
    hipMemsetAsync((char*)(px + (size_t)NN * PXC), 0, PXC * 2, stream);     // px sentinel row
    hipMemsetAsync((char*)(HB + (size_t)NN * 512), 0, 512 * 2, stream);     // h sentinel row
    hipMemsetAsync((char*)(Call + (size_t)NN * 512), 0, 512 * 4, stream);   // c sentinel row

    // dtype detect + merged normalize
    k_detect<<<16, 256, 0, stream>>>((const u32*)d_in[0], (const u32*)d_in[1], fcnt, pcnt);
    k_pnorm<<<32, 256, 0, stream>>>((const u32*)d_in[1], pcnt, pnorm);
    NormSrcs srcs;
    srcs.p[0] = d_in[0];  srcs.p[1] = d_in[2];  srcs.p[2] = d_in[10]; srcs.p[3] = d_in[4];
    srcs.p[4] = d_in[6];  srcs.p[5] = d_in[8];  srcs.p[6] = d_in[12]; srcs.p[7] = d_in[14];
    srcs.p[8] = d_in[3];  srcs.p[9] = d_in[5];  srcs.p[10] = d_in[7]; srcs.p[11] = d_in[9];
    srcs.p[12] = d_in[11]; srcs.p[13] = d_in[13]; srcs.p[14] = d_in[15];
    k_norm_all<<<2048, 256, 0, stream>>>(srcs, NGI, NW, NB, fcnt);

    // level schedule
    k_depth<<<32, 256, 0, stream>>>(pnorm, depth);
    k_hist<<<32, 256, 0, stream>>>(depth, counts);
    k_scan<<<1, 64, 0, stream>>>(counts, lvl);
    k_scatter<<<32, 256, 0, stream>>>(depth, lvl, cursor, order);

    // input projections
    dim3 gg(PXC / 256, NN / 32);
    k_gemm_in<<<gg, 256, 0, stream>>>(NGI, NW + NW_CSWX, NB + NB_CSBX, px);
    k_gemm_in<<<gg, 256, 0, stream>>>(NGI, NW + NW_CHWX, NB + NB_CHBX, qx);

    // child-sum: deepest -> root, one fused kernel per level
    for (int d = MAXD - 1; d >= 0; --d) {
        cs_lvl<<<LVL_GRID, TBLK, 0, stream>>>(d, order, lvl, pnorm,
                                              acc_h, acc_fc, acc_zc,
                                              NW + NW_CSWIO, NW + NW_CSWUM, NW + NW_CSWFZ,
                                              NB + NB_CSBIO, NB + NB_CSBUM, NB + NB_CSBFZ,
                                              px, d_out, fcnt);
    }
    // chain: root -> leaves
    for (int d = 0; d < MAXD; ++d) {
        ch_lvl<<<LVL_GRID, TBLK, 0, stream>>>(d, order, lvl, pnorm,
                                              HB, Call,
                                              NW + NW_CHWH, NW + NW_CHWUM,
                                              NB + NB_CHBH, NB + NB_CHBUM, qx);
    }

    // brep
    k_maxA<<<64, 256, 0, stream>>>(HB, pmax);
    k_maxB<<<1, 512, 0, stream>>>(pmax, d_out, fcnt);
}

// Round 7
// 1777.185 us; speedup vs baseline: 6.9640x; 2.5132x over previous
//
#include <hip/hip_runtime.h>
#include <hip/hip_bf16.h>

typedef unsigned short u16;
typedef unsigned int u32;

#define NN 8192
#define PXC 2560
#define MAXD 36
#define GY 48

typedef __attribute__((ext_vector_type(8))) short bf16x8;
typedef __attribute__((ext_vector_type(4))) float f32x4;

// ---------------- workspace layout (bytes) ----------------
static constexpr size_t SZ_PX  = (size_t)(NN + 1) * PXC * 2;   // bf16, row NN zero sentinel
static constexpr size_t SZ_ACC = (size_t)(NN + 1) * 512 * 4;   // f32
static constexpr size_t SZ_HB  = (size_t)(NN + 1) * 512 * 2;   // bf16
static constexpr size_t SZ_G   = (size_t)NN * 1536 * 4;        // f32 chain gates; transient normalized inputs
static constexpr size_t SZ_NW  = (size_t)5242880 * 2;          // bf16 normalized weights

static constexpr size_t OFF_PX    = 0;
static constexpr size_t OFF_QX    = OFF_PX + SZ_PX;
static constexpr size_t OFF_ACCH  = OFF_QX + SZ_PX;
static constexpr size_t OFF_ACCF  = OFF_ACCH + SZ_ACC;
static constexpr size_t OFF_ACCZ  = OFF_ACCF + SZ_ACC;
static constexpr size_t OFF_C     = OFF_ACCZ + SZ_ACC;         // c store (cs) / c_all (chain), f32
static constexpr size_t OFF_HB    = OFF_C + SZ_ACC;            // h store (cs) / h_all (chain), bf16
static constexpr size_t OFF_ZB    = OFF_HB + SZ_HB;            // chain ZB, bf16
static constexpr size_t OFF_G     = OFF_ZB + SZ_HB;            // chain sigma gates; transient normalized inputs
static constexpr size_t OFF_NW    = OFF_G + SZ_G;
static constexpr size_t OFF_DEPTH = OFF_NW + SZ_NW;
static constexpr size_t OFF_ORDER = OFF_DEPTH + (size_t)NN * 4;
static constexpr size_t OFF_MISC  = OFF_ORDER + (size_t)NN * 4;
static constexpr size_t OFF_LVL   = OFF_MISC + 1024;
static constexpr size_t OFF_NB    = OFF_LVL + 512;
static constexpr size_t OFF_PN    = OFF_NB + 20480;
static constexpr size_t OFF_PMAX  = OFF_PN + (size_t)NN * 4;   // f32 64*512
static constexpr size_t WS_TOTAL  = OFF_PMAX + (size_t)128 * 512 * 4;

#define NW_CSWX  0
#define NW_CHWX  1310720
#define NW_CSWIO 2621440
#define NW_CSWFZ 3145728
#define NW_CSWUM 3670016
#define NW_CHWH  3932160
#define NW_CHWUM 4980736

#define NB_CSBX  0
#define NB_CSBIO 2560
#define NB_CSBFZ 3584
#define NB_CSBUM 4608
#define NB_CHBX  5120
#define NB_CHBH  7680
#define NB_CHBUM 9728

// ---------------- helpers ----------------
__device__ __forceinline__ float bfu(u16 u) { return __uint_as_float(((u32)u) << 16); }
__device__ __forceinline__ u16 f2bf(float f) {
    u32 u = __float_as_uint(f);
    u += 0x7fffu + ((u >> 16) & 1u);
    return (u16)(u >> 16);
}
__device__ __forceinline__ float sigf(float x) {
    x = fminf(fmaxf(x, -30.f), 30.f);
    return 1.f / (1.f + __expf(-x));
}
__device__ __forceinline__ float tanhq(float x) {
    x = fminf(fmaxf(x, -15.f), 15.f);
    return 1.f - 2.f / (__expf(2.f * x) + 1.f);
}
__device__ __forceinline__ bf16x8 cvt8(const float* p) {
    float4 a = *(const float4*)p;
    float4 b = *(const float4*)(p + 4);
    union { u32 u[4]; bf16x8 v; } r;
    r.u[0] = ((__float_as_uint(a.x) + 0x8000u) >> 16) | ((__float_as_uint(a.y) + 0x8000u) & 0xffff0000u);
    r.u[1] = ((__float_as_uint(a.z) + 0x8000u) >> 16) | ((__float_as_uint(a.w) + 0x8000u) & 0xffff0000u);
    r.u[2] = ((__float_as_uint(b.x) + 0x8000u) >> 16) | ((__float_as_uint(b.y) + 0x8000u) & 0xffff0000u);
    r.u[3] = ((__float_as_uint(b.z) + 0x8000u) >> 16) | ((__float_as_uint(b.w) + 0x8000u) & 0xffff0000u);
    return r.v;
}

// ---------------- dtype detection + normalization ----------------
__global__ void k_detect(const u32* __restrict__ fin, const u32* __restrict__ pin,
                         int* __restrict__ fcnt, int* __restrict__ pcnt) {
    int i = blockIdx.x * 256 + threadIdx.x;
    if (i < 4096) {
        u32 w = fin[i];
        int e = (w >> 7) & 0xFF;
        if (w != 0u && e >= 0x70 && e <= 0x8F) atomicAdd(fcnt, 1);
    }
    if (i >= 1 && i < 4096) {
        if (pin[2 * i - 1] != 0u) atomicAdd(pcnt, 1);
    }
}

__global__ void k_pnorm(const u32* __restrict__ pin, const int* __restrict__ pcnt,
                        int* __restrict__ pnorm) {
    int i = blockIdx.x * 256 + threadIdx.x;
    if (i >= NN) return;
    bool is64 = (*pcnt < 100);
    pnorm[i] = (int)(is64 ? pin[2 * i] : pin[i]);
}

struct NormSrcs { const void* p[15]; };
__global__ __launch_bounds__(256) void k_norm_all(NormSrcs s, u16* __restrict__ NGI,
                                                  u16* __restrict__ NW, u16* __restrict__ NB,
                                                  const int* __restrict__ fcnt) {
    const int cum[16] = {0, 1048576, 1376256, 1703936, 1835008, 1966080, 2031616, 2293760,
                         2359296, 2359936, 2360192, 2360448, 2360576, 2361216, 2361728, 2361856};
    const int dof[15] = {0, NW_CSWX / 4, NW_CHWX / 4, NW_CSWIO / 4, NW_CSWFZ / 4, NW_CSWUM / 4,
                         NW_CHWH / 4, NW_CHWUM / 4, NB_CSBX / 4, NB_CSBIO / 4, NB_CSBFZ / 4,
                         NB_CSBUM / 4, NB_CHBX / 4, NB_CHBH / 4, NB_CHBUM / 4};
    bool isbf = (*fcnt > 2048);
    int total = 2361856;
    for (int i = blockIdx.x * 256 + threadIdx.x; i < total; i += gridDim.x * 256) {
        int seg = 0;
#pragma unroll
        for (int k = 1; k < 15; ++k) if (i >= cum[k]) seg = k;
        int off = i - cum[seg];
        u16* dbase = (seg == 0) ? NGI : (seg < 8 ? NW : NB);
        ushort4* dst = (ushort4*)dbase + dof[seg] + off;
        if (isbf) {
            *dst = ((const ushort4*)s.p[seg])[off];
        } else {
            float4 v = ((const float4*)s.p[seg])[off];
            ushort4 o; o.x = f2bf(v.x); o.y = f2bf(v.y); o.z = f2bf(v.z); o.w = f2bf(v.w);
            *dst = o;
        }
    }
}

// ---------------- level schedule ----------------
__global__ void k_depth(const int* __restrict__ parent, int* __restrict__ depth) {
    int i = blockIdx.x * 256 + threadIdx.x;
    if (i >= NN) return;
    int d = 0, p = parent[i];
    while (p != NN && p >= 0 && p < NN && d < 9000) { d++; p = parent[p]; }
    depth[i] = d;
}
__global__ void k_hist(const int* __restrict__ depth, int* __restrict__ counts) {
    int i = blockIdx.x * 256 + threadIdx.x;
    if (i >= NN) return;
    int d = depth[i]; if (d > 63) d = 63;
    atomicAdd(&counts[d], 1);
}
__global__ void k_scan(const int* __restrict__ counts, int* __restrict__ lvl) {
    if (threadIdx.x == 0) {
        int s = 0; lvl[0] = 0;
        for (int d = 0; d < 64; ++d) { s += counts[d]; lvl[d + 1] = s; }
    }
}
__global__ void k_scatter(const int* __restrict__ depth, const int* __restrict__ lvl,
                          int* __restrict__ cursor, int* __restrict__ order) {
    int i = blockIdx.x * 256 + threadIdx.x;
    if (i >= NN) return;
    int d = depth[i]; if (d > 63) d = 63;
    int pos = atomicAdd(&cursor[d], 1);
    order[lvl[d] + pos] = i;
}

// ---------------- input-projection GEMM: 32x64 per wave ----------------
__global__ __launch_bounds__(256) void k_gemm_in(const u16* __restrict__ A, const u16* __restrict__ W,
                                                 const u16* __restrict__ bias, u16* __restrict__ C) {
    int wv = threadIdx.x >> 6;
    int lane = threadIdx.x & 63;
    int r = lane & 15, q = lane >> 4;
    int m0 = blockIdx.y * 32;
    int n0 = blockIdx.x * 256 + wv * 64;
    const u16* ap0 = A + (size_t)(m0 + r) * 512 + q * 8;
    const u16* ap1 = ap0 + 16 * 512;
    const u16* pb[4];
#pragma unroll
    for (int jt = 0; jt < 4; ++jt) pb[jt] = W + (size_t)(n0 + jt * 16 + r) * 512 + q * 8;
    f32x4 acc0[4] = {}, acc1[4] = {};
#pragma unroll 4
    for (int k0 = 0; k0 < 512; k0 += 32) {
        bf16x8 a0 = *(const bf16x8*)(ap0 + k0);
        bf16x8 a1 = *(const bf16x8*)(ap1 + k0);
#pragma unroll
        for (int jt = 0; jt < 4; ++jt) {
            bf16x8 b = *(const bf16x8*)(pb[jt] + k0);
            acc0[jt] = __builtin_amdgcn_mfma_f32_16x16x32_bf16(a0, b, acc0[jt], 0, 0, 0);
            acc1[jt] = __builtin_amdgcn_mfma_f32_16x16x32_bf16(a1, b, acc1[jt], 0, 0, 0);
        }
    }
#pragma unroll
    for (int jt = 0; jt < 4; ++jt) {
        int c = n0 + jt * 16 + r;
        float bv = bfu(bias[c]);
        size_t b0 = (size_t)(m0 + q * 4) * PXC + c;
        size_t b1 = (size_t)(m0 + 16 + q * 4) * PXC + c;
#pragma unroll
        for (int i = 0; i < 4; ++i) {
            C[b0 + (size_t)i * PXC] = f2bf(acc0[jt][i] + bv);
            C[b1 + (size_t)i * PXC] = f2bf(acc1[jt][i] + bv);
        }
    }
}

// ---------------- child-sum phase 1: i,o,u gates -> c,h ; scatter h ----------------
// grid (32 colgroups, GY tile-stride), block = 64 (one wave owns 16 cols x 3 gates)
__global__ __launch_bounds__(64) void cs_s1(
    int d, const int* __restrict__ order, const int* __restrict__ lvl,
    const int* __restrict__ parent,
    float* acc_h, const float* __restrict__ acc_fc, const float* __restrict__ acc_zc,
    const u16* __restrict__ Wio, const u16* __restrict__ Wum,
    const u16* __restrict__ bio, const u16* __restrict__ bum,
    const u16* __restrict__ px,
    float* __restrict__ Cst, u16* __restrict__ HB,
    void* __restrict__ outv, const int* __restrict__ fcnt)
{
    int start = lvl[d], cnt = lvl[d + 1] - start;
    if (cnt <= 0) return;
    int ntiles = (cnt + 15) >> 4;
    int lane = threadIdx.x;
    int r = lane & 15, q = lane >> 4;
    int c0 = blockIdx.x * 16;
    const u16* pbi = Wio + (size_t)(c0 + r) * 512 + q * 8;
    const u16* pbo = Wio + (size_t)(512 + c0 + r) * 512 + q * 8;
    const u16* pbu = Wum + (size_t)(c0 + r) * 512 + q * 8;
    bool isbf = (*fcnt > 2048);

    for (int tile = blockIdx.y; tile < ntiles; tile += GY) {
        int tr = tile * 16 + r;
        int nodeR = (tr < cnt) ? order[start + tr] : NN;
        const float* pah = acc_h + (size_t)nodeR * 512 + q * 8;
        const float* paz = acc_zc + (size_t)nodeR * 512 + q * 8;
        f32x4 ai = {}, ao = {}, au = {};
#pragma unroll 4
        for (int ko = 0; ko < 512; ko += 32) {
            bf16x8 a_h = cvt8(pah + ko);
            bf16x8 a_z = cvt8(paz + ko);
            ai = __builtin_amdgcn_mfma_f32_16x16x32_bf16(a_h, *(const bf16x8*)(pbi + ko), ai, 0, 0, 0);
            ao = __builtin_amdgcn_mfma_f32_16x16x32_bf16(a_h, *(const bf16x8*)(pbo + ko), ao, 0, 0, 0);
            au = __builtin_amdgcn_mfma_f32_16x16x32_bf16(a_z, *(const bf16x8*)(pbu + ko), au, 0, 0, 0);
        }
        int col = c0 + r;
        float bi_ = bfu(bio[col]), bo_ = bfu(bio[512 + col]), bu_ = bfu(bum[col]);
#pragma unroll
        for (int i2 = 0; i2 < 4; ++i2) {
            int ti = tile * 16 + q * 4 + i2;
            if (ti >= cnt) continue;
            int ni = order[start + ti];
            int p = parent[ni];
            size_t pxb = (size_t)ni * PXC, nb = (size_t)ni * 512;
            float ig = sigf(bfu(px[pxb + col]) + ai[i2] + bi_);
            float og = sigf(bfu(px[pxb + 1024 + col]) + ao[i2] + bo_);
            float uu = tanhq(bfu(px[pxb + 2048 + col]) + au[i2] + bu_);
            float cc = ig * uu + acc_fc[nb + col];
            float h = og * tanhq(cc);
            Cst[nb + col] = cc;
            HB[nb + col] = f2bf(h);
            atomicAdd(&acc_h[(size_t)p * 512 + col], h);
            if (ni == 0) {
                if (isbf) ((u16*)outv)[col] = f2bf(h);
                else ((float*)outv)[col] = h;
            }
        }
    }
}

// ---------------- child-sum phase 2: f,z gates on h ; scatter to parents ----------------
__global__ __launch_bounds__(64) void cs_s2(
    int d, const int* __restrict__ order, const int* __restrict__ lvl,
    const int* __restrict__ parent,
    const u16* __restrict__ Wfz, const u16* __restrict__ bfz,
    const u16* __restrict__ px,
    const float* __restrict__ Cst, const u16* __restrict__ HB,
    float* __restrict__ acc_fc, float* __restrict__ acc_zc)
{
    int start = lvl[d], cnt = lvl[d + 1] - start;
    if (cnt <= 0) return;
    int ntiles = (cnt + 15) >> 4;
    int lane = threadIdx.x;
    int r = lane & 15, q = lane >> 4;
    int c0 = blockIdx.x * 16;
    const u16* pbf = Wfz + (size_t)(c0 + r) * 512 + q * 8;
    const u16* pbz = Wfz + (size_t)(512 + c0 + r) * 512 + q * 8;

    for (int tile = blockIdx.y; tile < ntiles; tile += GY) {
        int tr = tile * 16 + r;
        int nodeR = (tr < cnt) ? order[start + tr] : NN;
        const u16* pa = HB + (size_t)nodeR * 512 + q * 8;
        f32x4 af = {}, az = {};
#pragma unroll 4
        for (int ko = 0; ko < 512; ko += 32) {
            bf16x8 a = *(const bf16x8*)(pa + ko);
            af = __builtin_amdgcn_mfma_f32_16x16x32_bf16(a, *(const bf16x8*)(pbf + ko), af, 0, 0, 0);
            az = __builtin_amdgcn_mfma_f32_16x16x32_bf16(a, *(const bf16x8*)(pbz + ko), az, 0, 0, 0);
        }
        int col = c0 + r;
        float bf_ = bfu(bfz[col]), bz_ = bfu(bfz[512 + col]);
#pragma unroll
        for (int i2 = 0; i2 < 4; ++i2) {
            int ti = tile * 16 + q * 4 + i2;
            if (ti >= cnt) continue;
            int ni = order[start + ti];
            int p = parent[ni];
            size_t nb = (size_t)ni * 512, pb = (size_t)p * 512, ppx = (size_t)p * PXC;
            float cT = Cst[nb + col];
            float f = sigf(bfu(px[ppx + 512 + col]) + af[i2] + bf_);
            atomicAdd(&acc_fc[pb + col], f * cT);
            float z = sigf(bfu(px[ppx + 1536 + col]) + az[i2] + bz_);
            atomicAdd(&acc_zc[pb + col], z * tanhq(cT));
        }
    }
}

// ---------------- chain phase 1: 4-gate GEMM on parent h -> sigma gates + ZB ----------------
__global__ __launch_bounds__(64) void ch_s1(
    int d, const int* __restrict__ order, const int* __restrict__ lvl,
    const int* __restrict__ parent,
    const u16* __restrict__ HB, const float* __restrict__ Call,
    const u16* __restrict__ Wh, const u16* __restrict__ bh,
    const u16* __restrict__ qx,
    float* __restrict__ G, u16* __restrict__ ZB)
{
    int start = lvl[d], cnt = lvl[d + 1] - start;
    if (cnt <= 0) return;
    int ntiles = (cnt + 15) >> 4;
    int lane = threadIdx.x;
    int r = lane & 15, q = lane >> 4;
    int c0 = blockIdx.x * 16;
    const u16* pbi = Wh + (size_t)(c0 + r) * 512 + q * 8;
    const u16* pbo = Wh + (size_t)(512 + c0 + r) * 512 + q * 8;
    const u16* pbf = Wh + (size_t)(1024 + c0 + r) * 512 + q * 8;
    const u16* pbz = Wh + (size_t)(1536 + c0 + r) * 512 + q * 8;

    for (int tile = blockIdx.y; tile < ntiles; tile += GY) {
        int tr = tile * 16 + r;
        int nod = (tr < cnt) ? order[start + tr] : -1;
        int prow = (nod < 0) ? NN : parent[nod];
        const u16* pa = HB + (size_t)prow * 512 + q * 8;
        f32x4 gi = {}, go = {}, gf = {}, gz = {};
#pragma unroll 4
        for (int ko = 0; ko < 512; ko += 32) {
            bf16x8 a = *(const bf16x8*)(pa + ko);
            gi = __builtin_amdgcn_mfma_f32_16x16x32_bf16(a, *(const bf16x8*)(pbi + ko), gi, 0, 0, 0);
            go = __builtin_amdgcn_mfma_f32_16x16x32_bf16(a, *(const bf16x8*)(pbo + ko), go, 0, 0, 0);
            gf = __builtin_amdgcn_mfma_f32_16x16x32_bf16(a, *(const bf16x8*)(pbf + ko), gf, 0, 0, 0);
            gz = __builtin_amdgcn_mfma_f32_16x16x32_bf16(a, *(const bf16x8*)(pbz + ko), gz, 0, 0, 0);
        }
        int col = c0 + r;
        float bi_ = bfu(bh[col]), bo_ = bfu(bh[512 + col]);
        float bf_ = bfu(bh[1024 + col]), bz_ = bfu(bh[1536 + col]);
#pragma unroll
        for (int i2 = 0; i2 < 4; ++i2) {
            int ti = tile * 16 + q * 4 + i2;
            if (ti >= cnt) continue;
            int ni = order[start + ti];
            int p = parent[ni];
            size_t qb = (size_t)ni * PXC, gb = (size_t)ni * 1536, nb = (size_t)ni * 512;
            float si = sigf(bfu(qx[qb + col]) + gi[i2] + bi_);
            float so = sigf(bfu(qx[qb + 512 + col]) + go[i2] + bo_);
            float sf = sigf(bfu(qx[qb + 1024 + col]) + gf[i2] + bf_);
            float zg = sigf(bfu(qx[qb + 1536 + col]) + gz[i2] + bz_);
            G[gb + col] = si;
            G[gb + 512 + col] = so;
            G[gb + 1024 + col] = sf;
            ZB[nb + col] = f2bf(zg * tanhq(Call[(size_t)p * 512 + col]));
        }
    }
}

// ---------------- chain phase 2: u-GEMM on ZB -> c,h ----------------
__global__ __launch_bounds__(64) void ch_s2(
    int d, const int* __restrict__ order, const int* __restrict__ lvl,
    const int* __restrict__ parent,
    const u16* __restrict__ ZB, const u16* __restrict__ qx,
    const u16* __restrict__ Wum, const u16* __restrict__ bum,
    const float* __restrict__ G, float* __restrict__ Call, u16* __restrict__ HB)
{
    int start = lvl[d], cnt = lvl[d + 1] - start;
    if (cnt <= 0) return;
    int ntiles = (cnt + 15) >> 4;
    int lane = threadIdx.x;
    int r = lane & 15, q = lane >> 4;
    int c0 = blockIdx.x * 16;
    const u16* pbu = Wum + (size_t)(c0 + r) * 512 + q * 8;

    for (int tile = blockIdx.y; tile < ntiles; tile += GY) {
        int tr = tile * 16 + r;
        int nodeR = (tr < cnt) ? order[start + tr] : NN;
        const u16* pa = ZB + (size_t)nodeR * 512 + q * 8;
        f32x4 au = {};
#pragma unroll 4
        for (int ko = 0; ko < 512; ko += 32) {
            bf16x8 a = *(const bf16x8*)(pa + ko);
            au = __builtin_amdgcn_mfma_f32_16x16x32_bf16(a, *(const bf16x8*)(pbu + ko), au, 0, 0, 0);
        }
        int col = c0 + r;
        float bu_ = bfu(bum[col]);
#pragma unroll
        for (int i2 = 0; i2 < 4; ++i2) {
            int ti = tile * 16 + q * 4 + i2;
            if (ti >= cnt) continue;
            int ni = order[start + ti];
            int p = parent[ni];
            size_t qb = (size_t)ni * PXC, gb = (size_t)ni * 1536, nb = (size_t)ni * 512;
            float uu = tanhq(bfu(qx[qb + 2048 + col]) + au[i2] + bu_);
            float si = G[gb + col];
            float so = G[gb + 512 + col];
            float sf = G[gb + 1024 + col];
            float pc = Call[(size_t)p * 512 + col];
            float cc = si * uu + sf * pc;
            float h = so * tanhq(cc);
            Call[nb + col] = cc;
            HB[nb + col] = f2bf(h);
        }
    }
}

// ---------------- final max reduce ----------------
__global__ __launch_bounds__(256) void k_maxA(const u16* __restrict__ HB, float* __restrict__ pmax) {
    int b = blockIdx.x, t = threadIdx.x;
    float m1 = -1e30f, m2 = -1e30f;
    for (int rr = b * 128; rr < b * 128 + 128; ++rr) {
        m1 = fmaxf(m1, bfu(HB[(size_t)rr * 512 + t]));
        m2 = fmaxf(m2, bfu(HB[(size_t)rr * 512 + t + 256]));
    }
    pmax[(size_t)b * 512 + t] = m1; pmax[(size_t)b * 512 + t + 256] = m2;
}
__global__ void k_maxB(const float* __restrict__ pmax, void* __restrict__ outv,
                       const int* __restrict__ fcnt) {
    int j = threadIdx.x;
    float m = -1e30f;
    for (int b = 0; b < 64; ++b) m = fmaxf(m, pmax[(size_t)b * 512 + j]);
    bool isbf = (*fcnt > 2048);
    if (isbf) ((u16*)outv)[512 + j] = f2bf(m);
    else ((float*)outv)[512 + j] = m;
}

__global__ void k_wsfail(u16* out) {
    int i = blockIdx.x * 256 + threadIdx.x;
    if (i < 1024) out[i] = f2bf(12345.f);
}

// ---------------- launch ----------------
extern "C" void kernel_launch(void* const* d_in, const int* in_sizes, int n_in,
                              void* d_out, int out_size, void* d_ws, size_t ws_size,
                              hipStream_t stream) {
    char* base = (char*)d_ws;
    u16* px = (u16*)(base + OFF_PX);
    u16* qx = (u16*)(base + OFF_QX);
    float* acc_h = (float*)(base + OFF_ACCH);
    float* acc_fc = (float*)(base + OFF_ACCF);
    float* acc_zc = (float*)(base + OFF_ACCZ);
    float* Call = (float*)(base + OFF_C);
    u16* HB = (u16*)(base + OFF_HB);
    u16* ZB = (u16*)(base + OFF_ZB);
    float* G = (float*)(base + OFF_G);
    u16* NGI = (u16*)(base + OFF_G);
    u16* NW = (u16*)(base + OFF_NW);
    int* depth = (int*)(base + OFF_DEPTH);
    int* order = (int*)(base + OFF_ORDER);
    int* counts = (int*)(base + OFF_MISC);
    int* cursor = counts + 64;
    int* fcnt = counts + 128;
    int* pcnt = counts + 129;
    int* lvl = (int*)(base + OFF_LVL);
    u16* NB = (u16*)(base + OFF_NB);
    int* pnorm = (int*)(base + OFF_PN);
    float* pmax = (float*)(base + OFF_PMAX);

    if (ws_size < WS_TOTAL) { k_wsfail<<<4, 256, 0, stream>>>((u16*)d_out); return; }

    hipMemsetAsync(base + OFF_MISC, 0, 1024, stream);
    hipMemsetAsync(base + OFF_ACCH, 0, 3 * SZ_ACC, stream);                 // acc_h/fc/zc (+sentinels)
    hipMemsetAsync((char*)(px + (size_t)NN * PXC), 0, PXC * 2, stream);     // px sentinel row
    hipMemsetAsync((char*)(HB + (size_t)NN * 512), 0, 512 * 2, stream);     // h sentinel row
    hipMemsetAsync((char*)(ZB + (size_t)NN * 512), 0, 512 * 2, stream);     // ZB sentinel row
    hipMemsetAsync((char*)(Call + (size_t)NN * 512), 0, 512 * 4, stream);   // c sentinel row

    // dtype detect + merged normalize
    k_detect<<<16, 256, 0, stream>>>((const u32*)d_in[0], (const u32*)d_in[1], fcnt, pcnt);
    k_pnorm<<<32, 256, 0, stream>>>((const u32*)d_in[1], pcnt, pnorm);
    NormSrcs srcs;
    srcs.p[0] = d_in[0];  srcs.p[1] = d_in[2];  srcs.p[2] = d_in[10]; srcs.p[3] = d_in[4];
    srcs.p[4] = d_in[6];  srcs.p[5] = d_in[8];  srcs.p[6] = d_in[12]; srcs.p[7] = d_in[14];
    srcs.p[8] = d_in[3];  srcs.p[9] = d_in[5];  srcs.p[10] = d_in[7]; srcs.p[11] = d_in[9];
    srcs.p[12] = d_in[11]; srcs.p[13] = d_in[13]; srcs.p[14] = d_in[15];
    k_norm_all<<<2048, 256, 0, stream>>>(srcs, NGI, NW, NB, fcnt);

    // level schedule
    k_depth<<<32, 256, 0, stream>>>(pnorm, depth);
    k_hist<<<32, 256, 0, stream>>>(depth, counts);
    k_scan<<<1, 64, 0, stream>>>(counts, lvl);
    k_scatter<<<32, 256, 0, stream>>>(depth, lvl, cursor, order);

    // input projections
    dim3 gg(PXC / 256, NN / 32);
    k_gemm_in<<<gg, 256, 0, stream>>>(NGI, NW + NW_CSWX, NB + NB_CSBX, px);
    k_gemm_in<<<gg, 256, 0, stream>>>(NGI, NW + NW_CHWX, NB + NB_CHBX, qx);

    dim3 gl(32, GY);
    // child-sum: deepest -> root, 2 dispatches per level
    for (int d = MAXD - 1; d >= 0; --d) {
        cs_s1<<<gl, 64, 0, stream>>>(d, order, lvl, pnorm,
                                     acc_h, acc_fc, acc_zc,
                                     NW + NW_CSWIO, NW + NW_CSWUM,
                                     NB + NB_CSBIO, NB + NB_CSBUM,
                                     px, Call, HB, d_out, fcnt);
        cs_s2<<<gl, 64, 0, stream>>>(d, order, lvl, pnorm,
                                     NW + NW_CSWFZ, NB + NB_CSBFZ,
                                     px, Call, HB, acc_fc, acc_zc);
    }
    // chain: root -> leaves
    for (int d = 0; d < MAXD; ++d) {
        ch_s1<<<gl, 64, 0, stream>>>(d, order, lvl, pnorm,
                                     HB, Call, NW + NW_CHWH, NB + NB_CHBH,
                                     qx, G, ZB);
        ch_s2<<<gl, 64, 0, stream>>>(d, order, lvl, pnorm,
                                     ZB, qx, NW + NW_CHWUM, NB + NB_CHBUM,
                                     G, Call, HB);
    }

    // brep
    k_maxA<<<64, 256, 0, stream>>>(HB, pmax);
    k_maxB<<<1, 512, 0, stream>>>(pmax, d_out, fcnt);
}

// Round 8
// 1571.045 us; speedup vs baseline: 7.8778x; 1.1312x over previous
//
#include <hip/hip_runtime.h>
#include <hip/hip_bf16.h>

typedef unsigned short u16;
typedef unsigned int u32;

#define NN 8192
#define PXC 2560
#define MAXD 36
#define GY 64

typedef __attribute__((ext_vector_type(8))) short bf16x8;
typedef __attribute__((ext_vector_type(4))) float f32x4;

// ---------------- workspace layout (bytes) ----------------
static constexpr size_t SZ_PX  = (size_t)(NN + 1) * PXC * 2;   // bf16, row NN zero sentinel
static constexpr size_t SZ_ACC = (size_t)(NN + 1) * 512 * 4;   // f32
static constexpr size_t SZ_HB  = (size_t)(NN + 1) * 512 * 2;   // bf16
static constexpr size_t SZ_G   = (size_t)(NN + 1) * 1536 * 4;  // per-node scratch: chain si/so/sf f32 OR cs c(f32)+h(bf16); also transient normalized inputs
static constexpr size_t SZ_NW  = (size_t)5242880 * 2;          // bf16 normalized weights

static constexpr size_t OFF_PX    = 0;
static constexpr size_t OFF_QX    = OFF_PX + SZ_PX;
static constexpr size_t OFF_ACCH  = OFF_QX + SZ_PX;
static constexpr size_t OFF_ACCF  = OFF_ACCH + SZ_ACC;
static constexpr size_t OFF_ACCZ  = OFF_ACCF + SZ_ACC;
static constexpr size_t OFF_C     = OFF_ACCZ + SZ_ACC;         // c_all (chain), f32
static constexpr size_t OFF_HB    = OFF_C + SZ_ACC;            // h_all (chain), bf16
static constexpr size_t OFF_ZB    = OFF_HB + SZ_HB;            // chain ZB, bf16
static constexpr size_t OFF_G     = OFF_ZB + SZ_HB;            // per-node scratch / transient normalized inputs
static constexpr size_t OFF_NW    = OFF_G + SZ_G;
static constexpr size_t OFF_DEPTH = OFF_NW + SZ_NW;
static constexpr size_t OFF_ORDER = OFF_DEPTH + (size_t)NN * 4;
static constexpr size_t OFF_MISC  = OFF_ORDER + (size_t)NN * 4;
static constexpr size_t OFF_LVL   = OFF_MISC + 1024;
static constexpr size_t OFF_NB    = OFF_LVL + 512;
static constexpr size_t OFF_PN    = OFF_NB + 20480;
static constexpr size_t OFF_PMAX  = OFF_PN + (size_t)NN * 4;   // f32 64*512
static constexpr size_t WS_TOTAL  = OFF_PMAX + (size_t)128 * 512 * 4;

#define NW_CSWX  0
#define NW_CHWX  1310720
#define NW_CSWIO 2621440
#define NW_CSWFZ 3145728
#define NW_CSWUM 3670016
#define NW_CHWH  3932160
#define NW_CHWUM 4980736

#define NB_CSBX  0
#define NB_CSBIO 2560
#define NB_CSBFZ 3584
#define NB_CSBUM 4608
#define NB_CHBX  5120
#define NB_CHBH  7680
#define NB_CHBUM 9728

// ---------------- helpers ----------------
__device__ __forceinline__ float bfu(u16 u) { return __uint_as_float(((u32)u) << 16); }
__device__ __forceinline__ u16 f2bf(float f) {
    u32 u = __float_as_uint(f);
    u += 0x7fffu + ((u >> 16) & 1u);
    return (u16)(u >> 16);
}
__device__ __forceinline__ float sigf(float x) {
    x = fminf(fmaxf(x, -30.f), 30.f);
    return 1.f / (1.f + __expf(-x));
}
__device__ __forceinline__ float tanhq(float x) {
    x = fminf(fmaxf(x, -15.f), 15.f);
    return 1.f - 2.f / (__expf(2.f * x) + 1.f);
}
__device__ __forceinline__ bf16x8 cvt8(const float* p) {
    float4 a = *(const float4*)p;
    float4 b = *(const float4*)(p + 4);
    union { u32 u[4]; bf16x8 v; } r;
    r.u[0] = ((__float_as_uint(a.x) + 0x8000u) >> 16) | ((__float_as_uint(a.y) + 0x8000u) & 0xffff0000u);
    r.u[1] = ((__float_as_uint(a.z) + 0x8000u) >> 16) | ((__float_as_uint(a.w) + 0x8000u) & 0xffff0000u);
    r.u[2] = ((__float_as_uint(b.x) + 0x8000u) >> 16) | ((__float_as_uint(b.y) + 0x8000u) & 0xffff0000u);
    r.u[3] = ((__float_as_uint(b.z) + 0x8000u) >> 16) | ((__float_as_uint(b.w) + 0x8000u) & 0xffff0000u);
    return r.v;
}

// per-node scratch accessors (G region, 1536 f32 per node)
// cs:  c  -> f32 [node*1536 + 0 .. 512)
//      h  -> bf16 at u16 index [node*3072 + 1024 .. 1536)
// ch:  si/so/sf -> f32 [node*1536 + {0,512,1024} .. )

// ---------------- dtype detection + normalization ----------------
__global__ void k_detect(const u32* __restrict__ fin, const u32* __restrict__ pin,
                         int* __restrict__ fcnt, int* __restrict__ pcnt) {
    int i = blockIdx.x * 256 + threadIdx.x;
    if (i < 4096) {
        u32 w = fin[i];
        int e = (w >> 7) & 0xFF;
        if (w != 0u && e >= 0x70 && e <= 0x8F) atomicAdd(fcnt, 1);
    }
    if (i >= 1 && i < 4096) {
        if (pin[2 * i - 1] != 0u) atomicAdd(pcnt, 1);
    }
}

__global__ void k_pnorm(const u32* __restrict__ pin, const int* __restrict__ pcnt,
                        int* __restrict__ pnorm) {
    int i = blockIdx.x * 256 + threadIdx.x;
    if (i >= NN) return;
    bool is64 = (*pcnt < 100);
    pnorm[i] = (int)(is64 ? pin[2 * i] : pin[i]);
}

struct NormSrcs { const void* p[15]; };
__global__ __launch_bounds__(256) void k_norm_all(NormSrcs s, u16* __restrict__ NGI,
                                                  u16* __restrict__ NW, u16* __restrict__ NB,
                                                  const int* __restrict__ fcnt) {
    const int cum[16] = {0, 1048576, 1376256, 1703936, 1835008, 1966080, 2031616, 2293760,
                         2359296, 2359936, 2360192, 2360448, 2360576, 2361216, 2361728, 2361856};
    const int dof[15] = {0, NW_CSWX / 4, NW_CHWX / 4, NW_CSWIO / 4, NW_CSWFZ / 4, NW_CSWUM / 4,
                         NW_CHWH / 4, NW_CHWUM / 4, NB_CSBX / 4, NB_CSBIO / 4, NB_CSBFZ / 4,
                         NB_CSBUM / 4, NB_CHBX / 4, NB_CHBH / 4, NB_CHBUM / 4};
    bool isbf = (*fcnt > 2048);
    int total = 2361856;
    for (int i = blockIdx.x * 256 + threadIdx.x; i < total; i += gridDim.x * 256) {
        int seg = 0;
#pragma unroll
        for (int k = 1; k < 15; ++k) if (i >= cum[k]) seg = k;
        int off = i - cum[seg];
        u16* dbase = (seg == 0) ? NGI : (seg < 8 ? NW : NB);
        ushort4* dst = (ushort4*)dbase + dof[seg] + off;
        if (isbf) {
            *dst = ((const ushort4*)s.p[seg])[off];
        } else {
            float4 v = ((const float4*)s.p[seg])[off];
            ushort4 o; o.x = f2bf(v.x); o.y = f2bf(v.y); o.z = f2bf(v.z); o.w = f2bf(v.w);
            *dst = o;
        }
    }
}

// ---------------- level schedule ----------------
__global__ void k_depth(const int* __restrict__ parent, int* __restrict__ depth) {
    int i = blockIdx.x * 256 + threadIdx.x;
    if (i >= NN) return;
    int d = 0, p = parent[i];
    while (p != NN && p >= 0 && p < NN && d < 9000) { d++; p = parent[p]; }
    depth[i] = d;
}
__global__ void k_hist(const int* __restrict__ depth, int* __restrict__ counts) {
    int i = blockIdx.x * 256 + threadIdx.x;
    if (i >= NN) return;
    int d = depth[i]; if (d > 63) d = 63;
    atomicAdd(&counts[d], 1);
}
__global__ void k_scan(const int* __restrict__ counts, int* __restrict__ lvl) {
    if (threadIdx.x == 0) {
        int s = 0; lvl[0] = 0;
        for (int d = 0; d < 64; ++d) { s += counts[d]; lvl[d + 1] = s; }
    }
}
__global__ void k_scatter(const int* __restrict__ depth, const int* __restrict__ lvl,
                          int* __restrict__ cursor, int* __restrict__ order) {
    int i = blockIdx.x * 256 + threadIdx.x;
    if (i >= NN) return;
    int d = depth[i]; if (d > 63) d = 63;
    int pos = atomicAdd(&cursor[d], 1);
    order[lvl[d] + pos] = i;
}

// zero the sentinel rows chain reads for the root (HB[NN], Call[NN]) + px row-NN not needed (never read as data path that matters)
__global__ void k_init(u16* __restrict__ HB, float* __restrict__ Call) {
    int t = threadIdx.x + blockIdx.x * 256; // 512 threads
    if (t < 512) {
        HB[(size_t)NN * 512 + t] = 0;
        Call[(size_t)NN * 512 + t] = 0.f;
    }
}

// ---------------- merged input-projection GEMM: z=0 -> px(cs), z=1 -> qx(ch) ----------------
__global__ __launch_bounds__(256) void k_gemm_in(const u16* __restrict__ A,
                                                 const u16* __restrict__ Wcs, const u16* __restrict__ Wch,
                                                 const u16* __restrict__ bcs, const u16* __restrict__ bch,
                                                 u16* __restrict__ Ccs, u16* __restrict__ Cch) {
    const u16* W = blockIdx.z ? Wch : Wcs;
    const u16* bias = blockIdx.z ? bch : bcs;
    u16* C = blockIdx.z ? Cch : Ccs;
    int wv = threadIdx.x >> 6;
    int lane = threadIdx.x & 63;
    int r = lane & 15, q = lane >> 4;
    int m0 = blockIdx.y * 32;
    int n0 = blockIdx.x * 256 + wv * 64;
    const u16* ap0 = A + (size_t)(m0 + r) * 512 + q * 8;
    const u16* ap1 = ap0 + 16 * 512;
    const u16* pb[4];
#pragma unroll
    for (int jt = 0; jt < 4; ++jt) pb[jt] = W + (size_t)(n0 + jt * 16 + r) * 512 + q * 8;
    f32x4 acc0[4] = {}, acc1[4] = {};
#pragma unroll 4
    for (int k0 = 0; k0 < 512; k0 += 32) {
        bf16x8 a0 = *(const bf16x8*)(ap0 + k0);
        bf16x8 a1 = *(const bf16x8*)(ap1 + k0);
#pragma unroll
        for (int jt = 0; jt < 4; ++jt) {
            bf16x8 b = *(const bf16x8*)(pb[jt] + k0);
            acc0[jt] = __builtin_amdgcn_mfma_f32_16x16x32_bf16(a0, b, acc0[jt], 0, 0, 0);
            acc1[jt] = __builtin_amdgcn_mfma_f32_16x16x32_bf16(a1, b, acc1[jt], 0, 0, 0);
        }
    }
#pragma unroll
    for (int jt = 0; jt < 4; ++jt) {
        int c = n0 + jt * 16 + r;
        float bv = bfu(bias[c]);
        size_t b0 = (size_t)(m0 + q * 4) * PXC + c;
        size_t b1 = (size_t)(m0 + 16 + q * 4) * PXC + c;
#pragma unroll
        for (int i = 0; i < 4; ++i) {
            C[b0 + (size_t)i * PXC] = f2bf(acc0[jt][i] + bv);
            C[b1 + (size_t)i * PXC] = f2bf(acc1[jt][i] + bv);
        }
    }
}

// ---------------- combined phase-1: z=0 cs level dcs, z=1 ch level dch ----------------
__global__ __launch_bounds__(64) void comb_s1(
    int dcs, int dch,
    const int* __restrict__ order, const int* __restrict__ lvl, const int* __restrict__ parent,
    // cs
    float* acc_h, const float* __restrict__ acc_fc, const float* __restrict__ acc_zc,
    const u16* __restrict__ Wio, const u16* __restrict__ Wum,
    const u16* __restrict__ bio, const u16* __restrict__ bum,
    const u16* __restrict__ px,
    // ch
    const u16* __restrict__ HB, const float* __restrict__ Call,
    const u16* __restrict__ Wh, const u16* __restrict__ bh,
    const u16* __restrict__ qx, u16* __restrict__ ZB,
    // shared scratch
    float* __restrict__ G,
    void* __restrict__ outv, const int* __restrict__ fcnt)
{
    int lane = threadIdx.x;
    int r = lane & 15, q = lane >> 4;
    int c0 = blockIdx.x * 16;
    int col = c0 + r;
    u16* Gh = (u16*)G;

    if (blockIdx.z == 0) {
        // ---------- child-sum phase 1 ----------
        int d = dcs;
        int start = lvl[d], cnt = lvl[d + 1] - start;
        if (cnt <= 0) return;
        int ntiles = (cnt + 15) >> 4;
        const u16* pbi = Wio + (size_t)(c0 + r) * 512 + q * 8;
        const u16* pbo = Wio + (size_t)(512 + c0 + r) * 512 + q * 8;
        const u16* pbu = Wum + (size_t)(c0 + r) * 512 + q * 8;
        bool isbf = (*fcnt > 2048);
        for (int tile = blockIdx.y; tile < ntiles; tile += GY) {
            int tr = tile * 16 + r;
            int nodeR = (tr < cnt) ? order[start + tr] : NN;
            const float* pah = acc_h + (size_t)nodeR * 512 + q * 8;
            const float* paz = acc_zc + (size_t)nodeR * 512 + q * 8;
            f32x4 ai = {}, ao = {}, au = {};
#pragma unroll 4
            for (int ko = 0; ko < 512; ko += 32) {
                bf16x8 a_h = cvt8(pah + ko);
                bf16x8 a_z = cvt8(paz + ko);
                ai = __builtin_amdgcn_mfma_f32_16x16x32_bf16(a_h, *(const bf16x8*)(pbi + ko), ai, 0, 0, 0);
                ao = __builtin_amdgcn_mfma_f32_16x16x32_bf16(a_h, *(const bf16x8*)(pbo + ko), ao, 0, 0, 0);
                au = __builtin_amdgcn_mfma_f32_16x16x32_bf16(a_z, *(const bf16x8*)(pbu + ko), au, 0, 0, 0);
            }
            float bi_ = bfu(bio[col]), bo_ = bfu(bio[512 + col]), bu_ = bfu(bum[col]);
#pragma unroll
            for (int i2 = 0; i2 < 4; ++i2) {
                int ti = tile * 16 + q * 4 + i2;
                if (ti >= cnt) continue;
                int ni = order[start + ti];
                int p = parent[ni];
                size_t pxb = (size_t)ni * PXC, nb = (size_t)ni * 512;
                float ig = sigf(bfu(px[pxb + col]) + ai[i2] + bi_);
                float og = sigf(bfu(px[pxb + 1024 + col]) + ao[i2] + bo_);
                float uu = tanhq(bfu(px[pxb + 2048 + col]) + au[i2] + bu_);
                float cc = ig * uu + acc_fc[nb + col];
                float h = og * tanhq(cc);
                G[(size_t)ni * 1536 + col] = cc;                   // cs c
                Gh[(size_t)ni * 3072 + 1024 + col] = f2bf(h);      // cs h (bf16)
                atomicAdd(&acc_h[(size_t)p * 512 + col], h);
                if (ni == 0) {
                    if (isbf) ((u16*)outv)[col] = f2bf(h);
                    else ((float*)outv)[col] = h;
                }
            }
        }
    } else {
        // ---------- chain phase 1 ----------
        int d = dch;
        int start = lvl[d], cnt = lvl[d + 1] - start;
        if (cnt <= 0) return;
        int ntiles = (cnt + 15) >> 4;
        const u16* pbi = Wh + (size_t)(c0 + r) * 512 + q * 8;
        const u16* pbo = Wh + (size_t)(512 + c0 + r) * 512 + q * 8;
        const u16* pbf = Wh + (size_t)(1024 + c0 + r) * 512 + q * 8;
        const u16* pbz = Wh + (size_t)(1536 + c0 + r) * 512 + q * 8;
        for (int tile = blockIdx.y; tile < ntiles; tile += GY) {
            int tr = tile * 16 + r;
            int nod = (tr < cnt) ? order[start + tr] : -1;
            int prow = (nod < 0) ? NN : parent[nod];
            const u16* pa = HB + (size_t)prow * 512 + q * 8;
            f32x4 gi = {}, go = {}, gf = {}, gz = {};
#pragma unroll 4
            for (int ko = 0; ko < 512; ko += 32) {
                bf16x8 a = *(const bf16x8*)(pa + ko);
                gi = __builtin_amdgcn_mfma_f32_16x16x32_bf16(a, *(const bf16x8*)(pbi + ko), gi, 0, 0, 0);
                go = __builtin_amdgcn_mfma_f32_16x16x32_bf16(a, *(const bf16x8*)(pbo + ko), go, 0, 0, 0);
                gf = __builtin_amdgcn_mfma_f32_16x16x32_bf16(a, *(const bf16x8*)(pbf + ko), gf, 0, 0, 0);
                gz = __builtin_amdgcn_mfma_f32_16x16x32_bf16(a, *(const bf16x8*)(pbz + ko), gz, 0, 0, 0);
            }
            float bi_ = bfu(bh[col]), bo_ = bfu(bh[512 + col]);
            float bf_ = bfu(bh[1024 + col]), bz_ = bfu(bh[1536 + col]);
#pragma unroll
            for (int i2 = 0; i2 < 4; ++i2) {
                int ti = tile * 16 + q * 4 + i2;
                if (ti >= cnt) continue;
                int ni = order[start + ti];
                int p = parent[ni];
                size_t qb = (size_t)ni * PXC, gb = (size_t)ni * 1536, nb = (size_t)ni * 512;
                float si = sigf(bfu(qx[qb + col]) + gi[i2] + bi_);
                float so = sigf(bfu(qx[qb + 512 + col]) + go[i2] + bo_);
                float sf = sigf(bfu(qx[qb + 1024 + col]) + gf[i2] + bf_);
                float zg = sigf(bfu(qx[qb + 1536 + col]) + gz[i2] + bz_);
                G[gb + col] = si;
                G[gb + 512 + col] = so;
                G[gb + 1024 + col] = sf;
                ZB[nb + col] = f2bf(zg * tanhq(Call[(size_t)p * 512 + col]));
            }
        }
    }
}

// ---------------- combined phase-2 ----------------
__global__ __launch_bounds__(64) void comb_s2(
    int dcs, int dch,
    const int* __restrict__ order, const int* __restrict__ lvl, const int* __restrict__ parent,
    // cs
    const u16* __restrict__ Wfz, const u16* __restrict__ bfz,
    const u16* __restrict__ px,
    float* __restrict__ acc_fc, float* __restrict__ acc_zc,
    // ch
    const u16* __restrict__ ZB, const u16* __restrict__ qx,
    const u16* __restrict__ Wum, const u16* __restrict__ bum,
    float* __restrict__ Call, u16* __restrict__ HB,
    // shared scratch
    float* __restrict__ G)
{
    int lane = threadIdx.x;
    int r = lane & 15, q = lane >> 4;
    int c0 = blockIdx.x * 16;
    int col = c0 + r;
    const u16* Gh = (const u16*)G;

    if (blockIdx.z == 0) {
        // ---------- child-sum phase 2 ----------
        int d = dcs;
        int start = lvl[d], cnt = lvl[d + 1] - start;
        if (cnt <= 0) return;
        int ntiles = (cnt + 15) >> 4;
        const u16* pbf = Wfz + (size_t)(c0 + r) * 512 + q * 8;
        const u16* pbz = Wfz + (size_t)(512 + c0 + r) * 512 + q * 8;
        for (int tile = blockIdx.y; tile < ntiles; tile += GY) {
            int tr = tile * 16 + r;
            int nodeR = (tr < cnt) ? order[start + tr] : NN;
            const u16* pa = Gh + (size_t)nodeR * 3072 + 1024 + q * 8;   // cs h overlay
            f32x4 af = {}, az = {};
#pragma unroll 4
            for (int ko = 0; ko < 512; ko += 32) {
                bf16x8 a = *(const bf16x8*)(pa + ko);
                af = __builtin_amdgcn_mfma_f32_16x16x32_bf16(a, *(const bf16x8*)(pbf + ko), af, 0, 0, 0);
                az = __builtin_amdgcn_mfma_f32_16x16x32_bf16(a, *(const bf16x8*)(pbz + ko), az, 0, 0, 0);
            }
            float bf_ = bfu(bfz[col]), bz_ = bfu(bfz[512 + col]);
#pragma unroll
            for (int i2 = 0; i2 < 4; ++i2) {
                int ti = tile * 16 + q * 4 + i2;
                if (ti >= cnt) continue;
                int ni = order[start + ti];
                int p = parent[ni];
                size_t pb = (size_t)p * 512, ppx = (size_t)p * PXC;
                float cT = G[(size_t)ni * 1536 + col];               // cs c overlay
                float f = sigf(bfu(px[ppx + 512 + col]) + af[i2] + bf_);
                atomicAdd(&acc_fc[pb + col], f * cT);
                float z = sigf(bfu(px[ppx + 1536 + col]) + az[i2] + bz_);
                atomicAdd(&acc_zc[pb + col], z * tanhq(cT));
            }
        }
    } else {
        // ---------- chain phase 2 ----------
        int d = dch;
        int start = lvl[d], cnt = lvl[d + 1] - start;
        if (cnt <= 0) return;
        int ntiles = (cnt + 15) >> 4;
        const u16* pbu = Wum + (size_t)(c0 + r) * 512 + q * 8;
        for (int tile = blockIdx.y; tile < ntiles; tile += GY) {
            int tr = tile * 16 + r;
            int nodeR = (tr < cnt) ? order[start + tr] : NN;
            const u16* pa = ZB + (size_t)nodeR * 512 + q * 8;
            f32x4 au = {};
#pragma unroll 4
            for (int ko = 0; ko < 512; ko += 32) {
                bf16x8 a = *(const bf16x8*)(pa + ko);
                au = __builtin_amdgcn_mfma_f32_16x16x32_bf16(a, *(const bf16x8*)(pbu + ko), au, 0, 0, 0);
            }
            float bu_ = bfu(bum[col]);
#pragma unroll
            for (int i2 = 0; i2 < 4; ++i2) {
                int ti = tile * 16 + q * 4 + i2;
                if (ti >= cnt) continue;
                int ni = order[start + ti];
                int p = parent[ni];
                size_t qb = (size_t)ni * PXC, gb = (size_t)ni * 1536, nb = (size_t)ni * 512;
                float uu = tanhq(bfu(qx[qb + 2048 + col]) + au[i2] + bu_);
                float si = G[gb + col];
                float so = G[gb + 512 + col];
                float sf = G[gb + 1024 + col];
                float pc = Call[(size_t)p * 512 + col];
                float cc = si * uu + sf * pc;
                float h = so * tanhq(cc);
                Call[nb + col] = cc;
                HB[nb + col] = f2bf(h);
            }
        }
    }
}

// ---------------- final max reduce ----------------
__global__ __launch_bounds__(256) void k_maxA(const u16* __restrict__ HB, float* __restrict__ pmax) {
    int b = blockIdx.x, t = threadIdx.x;
    float m1 = -1e30f, m2 = -1e30f;
    for (int rr = b * 128; rr < b * 128 + 128; ++rr) {
        m1 = fmaxf(m1, bfu(HB[(size_t)rr * 512 + t]));
        m2 = fmaxf(m2, bfu(HB[(size_t)rr * 512 + t + 256]));
    }
    pmax[(size_t)b * 512 + t] = m1; pmax[(size_t)b * 512 + t + 256] = m2;
}
__global__ void k_maxB(const float* __restrict__ pmax, void* __restrict__ outv,
                       const int* __restrict__ fcnt) {
    int j = threadIdx.x;
    float m = -1e30f;
    for (int b = 0; b < 64; ++b) m = fmaxf(m, pmax[(size_t)b * 512 + j]);
    bool isbf = (*fcnt > 2048);
    if (isbf) ((u16*)outv)[512 + j] = f2bf(m);
    else ((float*)outv)[512 + j] = m;
}

__global__ void k_wsfail(u16* out) {
    int i = blockIdx.x * 256 + threadIdx.x;
    if (i < 1024) out[i] = f2bf(12345.f);
}

// ---------------- launch ----------------
extern "C" void kernel_launch(void* const* d_in, const int* in_sizes, int n_in,
                              void* d_out, int out_size, void* d_ws, size_t ws_size,
                              hipStream_t stream) {
    char* base = (char*)d_ws;
    u16* px = (u16*)(base + OFF_PX);
    u16* qx = (u16*)(base + OFF_QX);
    float* acc_h = (float*)(base + OFF_ACCH);
    float* acc_fc = (float*)(base + OFF_ACCF);
    float* acc_zc = (float*)(base + OFF_ACCZ);
    float* Call = (float*)(base + OFF_C);
    u16* HB = (u16*)(base + OFF_HB);
    u16* ZB = (u16*)(base + OFF_ZB);
    float* G = (float*)(base + OFF_G);
    u16* NGI = (u16*)(base + OFF_G);
    u16* NW = (u16*)(base + OFF_NW);
    int* depth = (int*)(base + OFF_DEPTH);
    int* order = (int*)(base + OFF_ORDER);
    int* counts = (int*)(base + OFF_MISC);
    int* cursor = counts + 64;
    int* fcnt = counts + 128;
    int* pcnt = counts + 129;
    int* lvl = (int*)(base + OFF_LVL);
    u16* NB = (u16*)(base + OFF_NB);
    int* pnorm = (int*)(base + OFF_PN);
    float* pmax = (float*)(base + OFF_PMAX);

    if (ws_size < WS_TOTAL) { k_wsfail<<<4, 256, 0, stream>>>((u16*)d_out); return; }

    hipMemsetAsync(base + OFF_MISC, 0, 1024, stream);
    hipMemsetAsync(base + OFF_ACCH, 0, 3 * SZ_ACC, stream);   // acc_h/fc/zc (+ sentinel rows)
    k_init<<<2, 256, 0, stream>>>(HB, Call);                   // HB[NN], Call[NN] = 0

    // dtype detect + merged normalize
    k_detect<<<16, 256, 0, stream>>>((const u32*)d_in[0], (const u32*)d_in[1], fcnt, pcnt);
    k_pnorm<<<32, 256, 0, stream>>>((const u32*)d_in[1], pcnt, pnorm);
    NormSrcs srcs;
    srcs.p[0] = d_in[0];  srcs.p[1] = d_in[2];  srcs.p[2] = d_in[10]; srcs.p[3] = d_in[4];
    srcs.p[4] = d_in[6];  srcs.p[5] = d_in[8];  srcs.p[6] = d_in[12]; srcs.p[7] = d_in[14];
    srcs.p[8] = d_in[3];  srcs.p[9] = d_in[5];  srcs.p[10] = d_in[7]; srcs.p[11] = d_in[9];
    srcs.p[12] = d_in[11]; srcs.p[13] = d_in[13]; srcs.p[14] = d_in[15];
    k_norm_all<<<2048, 256, 0, stream>>>(srcs, NGI, NW, NB, fcnt);

    // level schedule
    k_depth<<<32, 256, 0, stream>>>(pnorm, depth);
    k_hist<<<32, 256, 0, stream>>>(depth, counts);
    k_scan<<<1, 64, 0, stream>>>(counts, lvl);
    k_scatter<<<32, 256, 0, stream>>>(depth, lvl, cursor, order);

    // input projections (both in one dispatch; NGI consumed here, G reused after)
    dim3 gg(PXC / 256, NN / 32, 2);
    k_gemm_in<<<gg, 256, 0, stream>>>(NGI, NW + NW_CSWX, NW + NW_CHWX,
                                      NB + NB_CSBX, NB + NB_CHBX, px, qx);

    // fused levels: dispatch i runs cs level (35-i) and ch level (i)
    dim3 gl(32, GY, 2);
    for (int i = 0; i < MAXD; ++i) {
        int dcs = MAXD - 1 - i, dch = i;
        comb_s1<<<gl, 64, 0, stream>>>(dcs, dch, order, lvl, pnorm,
                                       acc_h, acc_fc, acc_zc,
                                       NW + NW_CSWIO, NW + NW_CSWUM,
                                       NB + NB_CSBIO, NB + NB_CSBUM, px,
                                       HB, Call, NW + NW_CHWH, NB + NB_CHBH,
                                       qx, ZB, G, d_out, fcnt);
        comb_s2<<<gl, 64, 0, stream>>>(dcs, dch, order, lvl, pnorm,
                                       NW + NW_CSWFZ, NB + NB_CSBFZ, px,
                                       acc_fc, acc_zc,
                                       ZB, qx, NW + NW_CHWUM, NB + NB_CHBUM,
                                       Call, HB, G);
    }

    // brep
    k_maxA<<<64, 256, 0, stream>>>(HB, pmax);
    k_maxB<<<1, 512, 0, stream>>>(pmax, d_out, fcnt);
}